// Round 1
// baseline (1412.485 us; speedup 1.0000x reference)
//
#include <hip/hip_runtime.h>

#define NN 100000
#define CIN 500
#define KPAD 512
#define HID 256
#define COUT 50
#define NPADOUT 64

typedef __attribute__((ext_vector_type(8))) short short8;
typedef __attribute__((ext_vector_type(4))) float f32x4;

static __device__ __forceinline__ unsigned short f2bf(float f) {
  union { float f; unsigned u; } v; v.f = f;
  unsigned r = (v.u + 0x7fffu + ((v.u >> 16) & 1u)) >> 16;
  return (unsigned short)r;
}

// ---------------- degree / CSR build ----------------

__global__ void k_count(const int* __restrict__ src, const int* __restrict__ dst,
                        int* __restrict__ deg, int* __restrict__ hist, int E) {
  int e = blockIdx.x * 256 + threadIdx.x;
  if (e < E) {
    atomicAdd(&deg[src[e]], 1);   // out-degree (reference: segment_sum over src)
    atomicAdd(&hist[dst[e]], 1);  // in-degree for CSR-by-dst
  }
}

__global__ void k_dinv(const int* __restrict__ deg, float* __restrict__ dinv, int n) {
  int i = blockIdx.x * 256 + threadIdx.x;
  if (i < n) {
    int d = deg[i];
    dinv[i] = d > 0 ? rsqrtf((float)d) : 0.f;
  }
}

// block-level inclusive scan of 1024 elements (256 thr x 4)
__global__ void k_scan_a(const int* __restrict__ hist, int* __restrict__ incl,
                         int* __restrict__ bsum, int n) {
  __shared__ int ts[256];
  int tid = threadIdx.x;
  int base = blockIdx.x * 1024 + tid * 4;
  int a0 = 0, a1 = 0, a2 = 0, a3 = 0;
  if (base + 3 < n) {
    a0 = hist[base]; a1 = hist[base + 1]; a2 = hist[base + 2]; a3 = hist[base + 3];
  } else {
    if (base     < n) a0 = hist[base];
    if (base + 1 < n) a1 = hist[base + 1];
    if (base + 2 < n) a2 = hist[base + 2];
    if (base + 3 < n) a3 = hist[base + 3];
  }
  a1 += a0; a2 += a1; a3 += a2;
  ts[tid] = a3;
  __syncthreads();
  for (int o = 1; o < 256; o <<= 1) {
    int v = ts[tid];
    if (tid >= o) v += ts[tid - o];
    __syncthreads();
    ts[tid] = v;
    __syncthreads();
  }
  int ex = tid ? ts[tid - 1] : 0;
  if (base     < n) incl[base]     = a0 + ex;
  if (base + 1 < n) incl[base + 1] = a1 + ex;
  if (base + 2 < n) incl[base + 2] = a2 + ex;
  if (base + 3 < n) incl[base + 3] = a3 + ex;
  if (tid == 255) bsum[blockIdx.x] = ts[255];
}

__global__ void k_scan_b(const int* __restrict__ bsum, int* __restrict__ bpre, int nb) {
  __shared__ int s[128];
  int tid = threadIdx.x;
  s[tid] = (tid < nb) ? bsum[tid] : 0;
  __syncthreads();
  for (int o = 1; o < 128; o <<= 1) {
    int v = s[tid];
    if (tid >= o) v += s[tid - o];
    __syncthreads();
    s[tid] = v;
    __syncthreads();
  }
  if (tid < nb) bpre[tid] = tid ? s[tid - 1] : 0;
}

__global__ void k_scan_c(const int* __restrict__ incl, const int* __restrict__ bpre,
                         int* __restrict__ offs, int n) {
  int g = blockIdx.x * 256 + threadIdx.x;
  if (g < n) {
    offs[g + 1] = incl[g] + bpre[g >> 10];
    if (g == 0) offs[0] = 0;
  }
}

__global__ void k_scatter(const int* __restrict__ src, const int* __restrict__ dst,
                          const float* __restrict__ dinv, const int* __restrict__ offs,
                          int* __restrict__ cur, int* __restrict__ csrc,
                          float* __restrict__ cnorm, int E) {
  int e = blockIdx.x * 256 + threadIdx.x;
  if (e < E) {
    int d = dst[e], s = src[e];
    int p = offs[d] + atomicAdd(&cur[d], 1);
    csrc[p] = s;
    cnorm[p] = dinv[s] * dinv[d];
  }
}

// ---------------- weight transpose+convert (tiny, once per call) ----------------

__global__ void k_w1t(const float* __restrict__ W1, unsigned short* __restrict__ W1T) {
  int idx = blockIdx.x * 256 + threadIdx.x;
  if (idx < HID * KPAD) {
    int n = idx >> 9, k = idx & 511;  // W1T[n][k], k-contiguous
    W1T[idx] = (k < CIN) ? f2bf(W1[(long)k * HID + n]) : (unsigned short)0;
  }
}

__global__ void k_w2t(const float* __restrict__ W2, unsigned short* __restrict__ W2T) {
  int idx = blockIdx.x * 256 + threadIdx.x;
  if (idx < NPADOUT * HID) {
    int n = idx >> 8, k = idx & 255;
    W2T[idx] = (n < COUT) ? f2bf(W2[(long)k * COUT + n]) : (unsigned short)0;
  }
}

// ---------------- GEMM1: h = relu(x @ W1 + b1), bf16 MFMA, 128x128 tile ----------------

__launch_bounds__(256)
__global__ void k_gemm1(const float* __restrict__ X, const unsigned short* __restrict__ W1T,
                        const float* __restrict__ b1, unsigned short* __restrict__ HB) {
  __shared__ unsigned short As[128 * 40];  // [m][k], row stride 40 bf16 (pad)
  __shared__ unsigned short Bs[128 * 40];  // [n][k]
  const int tid = threadIdx.x;
  const int lane = tid & 63, w = tid >> 6;
  const int wr = w >> 1, wc = w & 1;        // wave computes 64x64 sub-tile
  const int row0 = blockIdx.x * 128;
  const int n0 = blockIdx.y * 128;
  f32x4 acc[4][4] = {};
  const int sr = tid >> 3, sc = tid & 7;    // A staging: 32 rows/pass, 8 float4 chunks/row
  const int br = tid >> 2, bc = tid & 3;    // B staging: 64 rows/pass, 4 x8-chunks/row

  for (int kk = 0; kk < KPAD; kk += 32) {
    __syncthreads();
    // stage A: 128x32 fp32 -> bf16 (on-the-fly convert)
#pragma unroll
    for (int p = 0; p < 4; p++) {
      int r = sr + p * 32;
      int grow = row0 + r;
      int gk = kk + sc * 4;
      ushort4 val;
      if (grow < NN && gk < CIN) {
        const float4 f = *reinterpret_cast<const float4*>(&X[(long)grow * CIN + gk]);
        val.x = f2bf(f.x); val.y = f2bf(f.y); val.z = f2bf(f.z); val.w = f2bf(f.w);
      } else {
        val.x = val.y = val.z = val.w = 0;
      }
      *reinterpret_cast<ushort4*>(&As[r * 40 + sc * 4]) = val;
    }
    // stage B: 128x32 bf16 (already transposed/converted)
#pragma unroll
    for (int p = 0; p < 2; p++) {
      int nl = br + p * 64;
      const uint4 v = *reinterpret_cast<const uint4*>(&W1T[(long)(n0 + nl) * KPAD + kk + bc * 8]);
      *reinterpret_cast<uint4*>(&Bs[nl * 40 + bc * 8]) = v;
    }
    __syncthreads();
    // compute: 16 MFMA per wave per K-step
    short8 af[4], bfr[4];
    const int koff = (lane >> 4) * 8;
#pragma unroll
    for (int i = 0; i < 4; i++)
      af[i] = *reinterpret_cast<const short8*>(&As[(wr * 64 + i * 16 + (lane & 15)) * 40 + koff]);
#pragma unroll
    for (int j = 0; j < 4; j++)
      bfr[j] = *reinterpret_cast<const short8*>(&Bs[(wc * 64 + j * 16 + (lane & 15)) * 40 + koff]);
#pragma unroll
    for (int i = 0; i < 4; i++)
#pragma unroll
      for (int j = 0; j < 4; j++)
        acc[i][j] = __builtin_amdgcn_mfma_f32_16x16x32_bf16(af[i], bfr[j], acc[i][j], 0, 0, 0);
  }
  // epilogue: + b1, relu, -> bf16
#pragma unroll
  for (int i = 0; i < 4; i++) {
    int rbase = row0 + wr * 64 + i * 16 + (lane >> 4) * 4;
#pragma unroll
    for (int j = 0; j < 4; j++) {
      int col = n0 + wc * 64 + j * 16 + (lane & 15);
      float bv = b1[col];
#pragma unroll
      for (int r = 0; r < 4; r++) {
        int row = rbase + r;
        if (row < NN) {
          float v = acc[i][j][r] + bv;
          v = v > 0.f ? v : 0.f;
          HB[(long)row * HID + col] = f2bf(v);
        }
      }
    }
  }
}

// ---------------- GEMM2: out = h @ W2 + b2; writes x0 and hid = temp[0]*x0 ----------------

__launch_bounds__(256)
__global__ void k_gemm2(const unsigned short* __restrict__ HB, const unsigned short* __restrict__ W2T,
                        const float* __restrict__ b2, const float* __restrict__ temp,
                        float* __restrict__ X0, float* __restrict__ HIDB) {
  __shared__ unsigned short As[128 * 40];
  __shared__ unsigned short Bs[64 * 40];
  const int tid = threadIdx.x;
  const int lane = tid & 63, w = tid >> 6;  // wave computes 32x64 sub-tile
  const int row0 = blockIdx.x * 128;
  f32x4 acc[2][4] = {};
  const int ar = tid >> 2, ac = tid & 3;

  for (int kk = 0; kk < HID; kk += 32) {
    __syncthreads();
#pragma unroll
    for (int p = 0; p < 2; p++) {
      int r = ar + p * 64;
      int grow = row0 + r;
      uint4 v;
      if (grow < NN) v = *reinterpret_cast<const uint4*>(&HB[(long)grow * HID + kk + ac * 8]);
      else { v.x = v.y = v.z = v.w = 0; }
      *reinterpret_cast<uint4*>(&As[r * 40 + ac * 8]) = v;
    }
    {
      int nl = tid >> 2, c = tid & 3;
      const uint4 v = *reinterpret_cast<const uint4*>(&W2T[nl * HID + kk + c * 8]);
      *reinterpret_cast<uint4*>(&Bs[nl * 40 + c * 8]) = v;
    }
    __syncthreads();
    short8 af[2], bfr[4];
    const int koff = (lane >> 4) * 8;
#pragma unroll
    for (int i = 0; i < 2; i++)
      af[i] = *reinterpret_cast<const short8*>(&As[(w * 32 + i * 16 + (lane & 15)) * 40 + koff]);
#pragma unroll
    for (int j = 0; j < 4; j++)
      bfr[j] = *reinterpret_cast<const short8*>(&Bs[(j * 16 + (lane & 15)) * 40 + koff]);
#pragma unroll
    for (int i = 0; i < 2; i++)
#pragma unroll
      for (int j = 0; j < 4; j++)
        acc[i][j] = __builtin_amdgcn_mfma_f32_16x16x32_bf16(af[i], bfr[j], acc[i][j], 0, 0, 0);
  }
  float t0 = temp[0];
#pragma unroll
  for (int i = 0; i < 2; i++) {
    int rbase = row0 + w * 32 + i * 16 + (lane >> 4) * 4;
#pragma unroll
    for (int j = 0; j < 4; j++) {
      int col = j * 16 + (lane & 15);
      if (col < COUT) {
        float bv = b2[col];
#pragma unroll
        for (int r = 0; r < 4; r++) {
          int row = rbase + r;
          if (row < NN) {
            float v = acc[i][j][r] + bv;
            X0[(long)row * COUT + col] = v;
            HIDB[(long)row * COUT + col] = t0 * v;
          }
        }
      }
    }
  }
}

// ---------------- propagation: one wave per dst node, lanes = features ----------------

__launch_bounds__(256)
__global__ void k_prop(const int* __restrict__ offs, const int* __restrict__ csrc,
                       const float* __restrict__ cnorm, const float* __restrict__ xin,
                       float* __restrict__ xout, float* __restrict__ hid,
                       const float* __restrict__ temp, int accidx) {
  int node = blockIdx.x * 4 + (threadIdx.x >> 6);
  if (node >= NN) return;
  int f = threadIdx.x & 63;
  int fc = f < COUT ? f : 0;  // inactive lanes read lane0's column (discarded)
  int s0 = offs[node], s1 = offs[node + 1];
  float acc = 0.f;
  int e = s0;
  for (; e + 3 < s1; e += 4) {
    int a0 = csrc[e], a1 = csrc[e + 1], a2 = csrc[e + 2], a3 = csrc[e + 3];
    float w0 = cnorm[e], w1 = cnorm[e + 1], w2 = cnorm[e + 2], w3 = cnorm[e + 3];
    float v0 = xin[(long)a0 * COUT + fc];
    float v1 = xin[(long)a1 * COUT + fc];
    float v2 = xin[(long)a2 * COUT + fc];
    float v3 = xin[(long)a3 * COUT + fc];
    acc += w0 * v0 + w1 * v1 + w2 * v2 + w3 * v3;
  }
  for (; e < s1; e++) acc += cnorm[e] * xin[(long)csrc[e] * COUT + fc];
  if (f < COUT) {
    xout[(long)node * COUT + f] = acc;
    if (accidx >= 0) hid[(long)node * COUT + f] += temp[accidx] * acc;
  }
}

// ---------------- log_softmax over 50 cols, one wave per row ----------------

__launch_bounds__(256)
__global__ void k_lsm(const float* __restrict__ hid, float* __restrict__ out) {
  int node = blockIdx.x * 4 + (threadIdx.x >> 6);
  if (node >= NN) return;
  int f = threadIdx.x & 63;
  float v = (f < COUT) ? hid[(long)node * COUT + f] : -INFINITY;
  float m = v;
#pragma unroll
  for (int o = 32; o > 0; o >>= 1) m = fmaxf(m, __shfl_xor(m, o, 64));
  float ex = (f < COUT) ? expf(v - m) : 0.f;
  float s = ex;
#pragma unroll
  for (int o = 32; o > 0; o >>= 1) s += __shfl_xor(s, o, 64);
  if (f < COUT) out[(long)node * COUT + f] = (v - m) - logf(s);
}

// ---------------- launch ----------------

extern "C" void kernel_launch(void* const* d_in, const int* in_sizes, int n_in,
                              void* d_out, int out_size, void* d_ws, size_t ws_size,
                              hipStream_t stream) {
  const float* X  = (const float*)d_in[0];
  const int* EI   = (const int*)d_in[1];
  const float* W1 = (const float*)d_in[2];
  const float* B1 = (const float*)d_in[3];
  const float* W2 = (const float*)d_in[4];
  const float* B2 = (const float*)d_in[5];
  const float* TEMP = (const float*)d_in[6];
  const int E = in_sizes[1] / 2;
  const int* src = EI;
  const int* dst = EI + E;

  char* ws = (char*)d_ws;
  size_t off = 0;
  auto alloc = [&](size_t bytes) -> void* {
    off = (off + 511) & ~(size_t)511;
    void* p = ws + off;
    off += bytes;
    return p;
  };
  unsigned short* HB  = (unsigned short*)alloc((size_t)NN * HID * 2);
  unsigned short* W1T = (unsigned short*)alloc((size_t)HID * KPAD * 2);
  unsigned short* W2T = (unsigned short*)alloc((size_t)NPADOUT * HID * 2);
  float* X0   = (float*)alloc((size_t)NN * COUT * 4);
  float* X1   = (float*)alloc((size_t)NN * COUT * 4);
  float* HIDB = (float*)alloc((size_t)NN * COUT * 4);
  float* DINV = (float*)alloc((size_t)NN * 4);
  int* DEG    = (int*)alloc((size_t)NN * 4);
  int* HIST   = (int*)alloc((size_t)NN * 4);
  int* CUR    = (int*)alloc((size_t)NN * 4);
  int* OFFS   = (int*)alloc((size_t)(NN + 1) * 4);
  int* INCL   = (int*)alloc((size_t)NN * 4);
  int* BSUM   = (int*)alloc(128 * 4);
  int* BPRE   = (int*)alloc(128 * 4);
  int* CSRC   = (int*)alloc((size_t)E * 4);
  float* CNORM = (float*)alloc((size_t)E * 4);

  hipMemsetAsync(DEG, 0, (size_t)NN * 4, stream);
  hipMemsetAsync(HIST, 0, (size_t)NN * 4, stream);
  hipMemsetAsync(CUR, 0, (size_t)NN * 4, stream);

  const int EB = (E + 255) / 256;
  const int NB1 = (NN + 255) / 256;
  const int NBS = (NN + 1023) / 1024;  // 98 scan blocks

  k_count<<<EB, 256, 0, stream>>>(src, dst, DEG, HIST, E);
  k_dinv<<<NB1, 256, 0, stream>>>(DEG, DINV, NN);
  k_scan_a<<<NBS, 256, 0, stream>>>(HIST, INCL, BSUM, NN);
  k_scan_b<<<1, 128, 0, stream>>>(BSUM, BPRE, NBS);
  k_scan_c<<<NB1, 256, 0, stream>>>(INCL, BPRE, OFFS, NN);
  k_scatter<<<EB, 256, 0, stream>>>(src, dst, DINV, OFFS, CUR, CSRC, CNORM, E);

  k_w1t<<<(HID * KPAD + 255) / 256, 256, 0, stream>>>(W1, W1T);
  k_w2t<<<(NPADOUT * HID + 255) / 256, 256, 0, stream>>>(W2, W2T);

  dim3 g1((NN + 127) / 128, 2);
  k_gemm1<<<g1, 256, 0, stream>>>(X, W1T, B1, HB);
  k_gemm2<<<(NN + 127) / 128, 256, 0, stream>>>(HB, W2T, B2, TEMP, X0, HIDB);

  const int PB = (NN + 3) / 4;
  for (int k = 0; k < 5; k++) {
    k_prop<<<PB, 256, 0, stream>>>(OFFS, CSRC, CNORM, X0, X1, HIDB, TEMP, -1);
    k_prop<<<PB, 256, 0, stream>>>(OFFS, CSRC, CNORM, X1, X0, HIDB, TEMP, k + 1);
  }
  k_lsm<<<PB, 256, 0, stream>>>(HIDB, (float*)d_out);
}

// Round 2
// 1077.245 us; speedup vs baseline: 1.3112x; 1.3112x over previous
//
#include <hip/hip_runtime.h>

#define NN 100000
#define CIN 500
#define KPAD 512
#define HID 256
#define COUT 50
#define NPADOUT 64

typedef __attribute__((ext_vector_type(8))) short short8;
typedef __attribute__((ext_vector_type(4))) float f32x4;

static __device__ __forceinline__ unsigned short f2bf(float f) {
  union { float f; unsigned u; } v; v.f = f;
  unsigned r = (v.u + 0x7fffu + ((v.u >> 16) & 1u)) >> 16;
  return (unsigned short)r;
}

// ---------------- degree / CSR build ----------------

__global__ void k_count(const int* __restrict__ src, const int* __restrict__ dst,
                        int* __restrict__ deg, int* __restrict__ hist, int E) {
  int e = blockIdx.x * 256 + threadIdx.x;
  if (e < E) {
    atomicAdd(&deg[src[e]], 1);
    atomicAdd(&hist[dst[e]], 1);
  }
}

__global__ void k_dinv(const int* __restrict__ deg, float* __restrict__ dinv, int n) {
  int i = blockIdx.x * 256 + threadIdx.x;
  if (i < n) {
    int d = deg[i];
    dinv[i] = d > 0 ? rsqrtf((float)d) : 0.f;
  }
}

__global__ void k_scan_a(const int* __restrict__ hist, int* __restrict__ incl,
                         int* __restrict__ bsum, int n) {
  __shared__ int ts[256];
  int tid = threadIdx.x;
  int base = blockIdx.x * 1024 + tid * 4;
  int a0 = 0, a1 = 0, a2 = 0, a3 = 0;
  if (base + 3 < n) {
    a0 = hist[base]; a1 = hist[base + 1]; a2 = hist[base + 2]; a3 = hist[base + 3];
  } else {
    if (base     < n) a0 = hist[base];
    if (base + 1 < n) a1 = hist[base + 1];
    if (base + 2 < n) a2 = hist[base + 2];
    if (base + 3 < n) a3 = hist[base + 3];
  }
  a1 += a0; a2 += a1; a3 += a2;
  ts[tid] = a3;
  __syncthreads();
  for (int o = 1; o < 256; o <<= 1) {
    int v = ts[tid];
    if (tid >= o) v += ts[tid - o];
    __syncthreads();
    ts[tid] = v;
    __syncthreads();
  }
  int ex = tid ? ts[tid - 1] : 0;
  if (base     < n) incl[base]     = a0 + ex;
  if (base + 1 < n) incl[base + 1] = a1 + ex;
  if (base + 2 < n) incl[base + 2] = a2 + ex;
  if (base + 3 < n) incl[base + 3] = a3 + ex;
  if (tid == 255) bsum[blockIdx.x] = ts[255];
}

__global__ void k_scan_b(const int* __restrict__ bsum, int* __restrict__ bpre, int nb) {
  __shared__ int s[128];
  int tid = threadIdx.x;
  s[tid] = (tid < nb) ? bsum[tid] : 0;
  __syncthreads();
  for (int o = 1; o < 128; o <<= 1) {
    int v = s[tid];
    if (tid >= o) v += s[tid - o];
    __syncthreads();
    s[tid] = v;
    __syncthreads();
  }
  if (tid < nb) bpre[tid] = tid ? s[tid - 1] : 0;
}

__global__ void k_scan_c(const int* __restrict__ incl, const int* __restrict__ bpre,
                         int* __restrict__ offs, int n) {
  int g = blockIdx.x * 256 + threadIdx.x;
  if (g < n) {
    offs[g + 1] = incl[g] + bpre[g >> 10];
    if (g == 0) offs[0] = 0;
  }
}

__global__ void k_scatter(const int* __restrict__ src, const int* __restrict__ dst,
                          const float* __restrict__ dinv, const int* __restrict__ offs,
                          int* __restrict__ cur, int* __restrict__ csrc,
                          float* __restrict__ cnorm, int E) {
  int e = blockIdx.x * 256 + threadIdx.x;
  if (e < E) {
    int d = dst[e], s = src[e];
    int p = offs[d] + atomicAdd(&cur[d], 1);
    csrc[p] = s;
    cnorm[p] = dinv[s] * dinv[d];
  }
}

// ---------------- weight transpose+convert ----------------

__global__ void k_w1t(const float* __restrict__ W1, unsigned short* __restrict__ W1T) {
  int idx = blockIdx.x * 256 + threadIdx.x;
  if (idx < HID * KPAD) {
    int n = idx >> 9, k = idx & 511;
    W1T[idx] = (k < CIN) ? f2bf(W1[(long)k * HID + n]) : (unsigned short)0;
  }
}

__global__ void k_w2t(const float* __restrict__ W2, unsigned short* __restrict__ W2T) {
  int idx = blockIdx.x * 256 + threadIdx.x;
  if (idx < NPADOUT * HID) {
    int n = idx >> 8, k = idx & 255;
    W2T[idx] = (n < COUT) ? f2bf(W2[(long)k * COUT + n]) : (unsigned short)0;
  }
}

// ---------------- GEMM1: 128x256 tile per block (X streamed once), 512 thr ----------------

__launch_bounds__(512)
__global__ void k_gemm1(const float* __restrict__ X, const unsigned short* __restrict__ W1T,
                        const float* __restrict__ b1, unsigned short* __restrict__ HB) {
  __shared__ unsigned short As[128 * 40];  // [m][k] bf16, pad stride 40
  __shared__ unsigned short Bs[256 * 40];  // [n][k] bf16
  const int tid = threadIdx.x;
  const int lane = tid & 63, w = tid >> 6;  // 8 waves
  const int wr = w >> 2, wc = w & 3;        // 2x4 waves of 64x64 subtiles
  const int row0 = blockIdx.x * 128;
  f32x4 acc[4][4] = {};
  const int sr = tid >> 3, sc = tid & 7;    // A: 64 rows/pass, 8 float4/row
  const int br = tid >> 2, bc = tid & 3;    // B: 128 rows/pass, 4 x8/row

  for (int kk = 0; kk < KPAD; kk += 32) {
    __syncthreads();
#pragma unroll
    for (int p = 0; p < 2; p++) {
      int r = sr + p * 64;
      int grow = row0 + r;
      int gk = kk + sc * 4;
      ushort4 val;
      if (grow < NN && gk < CIN) {  // CIN%4==0 so gk<CIN implies gk+3<CIN
        const float4 f = *reinterpret_cast<const float4*>(&X[(long)grow * CIN + gk]);
        val.x = f2bf(f.x); val.y = f2bf(f.y); val.z = f2bf(f.z); val.w = f2bf(f.w);
      } else {
        val.x = val.y = val.z = val.w = 0;
      }
      *reinterpret_cast<ushort4*>(&As[r * 40 + sc * 4]) = val;
    }
#pragma unroll
    for (int p = 0; p < 2; p++) {
      int nl = br + p * 128;
      const uint4 v = *reinterpret_cast<const uint4*>(&W1T[(long)nl * KPAD + kk + bc * 8]);
      *reinterpret_cast<uint4*>(&Bs[nl * 40 + bc * 8]) = v;
    }
    __syncthreads();
    short8 af[4], bfr[4];
    const int koff = (lane >> 4) * 8;
#pragma unroll
    for (int i = 0; i < 4; i++)
      af[i] = *reinterpret_cast<const short8*>(&As[(wr * 64 + i * 16 + (lane & 15)) * 40 + koff]);
#pragma unroll
    for (int j = 0; j < 4; j++)
      bfr[j] = *reinterpret_cast<const short8*>(&Bs[(wc * 64 + j * 16 + (lane & 15)) * 40 + koff]);
#pragma unroll
    for (int i = 0; i < 4; i++)
#pragma unroll
      for (int j = 0; j < 4; j++)
        acc[i][j] = __builtin_amdgcn_mfma_f32_16x16x32_bf16(af[i], bfr[j], acc[i][j], 0, 0, 0);
  }
#pragma unroll
  for (int i = 0; i < 4; i++) {
    int rbase = row0 + wr * 64 + i * 16 + (lane >> 4) * 4;
#pragma unroll
    for (int j = 0; j < 4; j++) {
      int col = wc * 64 + j * 16 + (lane & 15);
      float bv = b1[col];
#pragma unroll
      for (int r = 0; r < 4; r++) {
        int row = rbase + r;
        if (row < NN) {
          float v = acc[i][j][r] + bv;
          v = v > 0.f ? v : 0.f;
          HB[(long)row * HID + col] = f2bf(v);
        }
      }
    }
  }
}

// ---------------- GEMM2: out = h @ W2 + b2; writes x0 (bf16) and hid = temp[0]*x0 ----------------

__launch_bounds__(256)
__global__ void k_gemm2(const unsigned short* __restrict__ HB, const unsigned short* __restrict__ W2T,
                        const float* __restrict__ b2, const float* __restrict__ temp,
                        unsigned short* __restrict__ X0B, float* __restrict__ HIDB) {
  __shared__ unsigned short As[128 * 40];
  __shared__ unsigned short Bs[64 * 40];
  const int tid = threadIdx.x;
  const int lane = tid & 63, w = tid >> 6;
  const int row0 = blockIdx.x * 128;
  f32x4 acc[2][4] = {};
  const int ar = tid >> 2, ac = tid & 3;

  for (int kk = 0; kk < HID; kk += 32) {
    __syncthreads();
#pragma unroll
    for (int p = 0; p < 2; p++) {
      int r = ar + p * 64;
      int grow = row0 + r;
      uint4 v;
      if (grow < NN) v = *reinterpret_cast<const uint4*>(&HB[(long)grow * HID + kk + ac * 8]);
      else { v.x = v.y = v.z = v.w = 0; }
      *reinterpret_cast<uint4*>(&As[r * 40 + ac * 8]) = v;
    }
    {
      int nl = tid >> 2, c = tid & 3;
      const uint4 v = *reinterpret_cast<const uint4*>(&W2T[nl * HID + kk + c * 8]);
      *reinterpret_cast<uint4*>(&Bs[nl * 40 + c * 8]) = v;
    }
    __syncthreads();
    short8 af[2], bfr[4];
    const int koff = (lane >> 4) * 8;
#pragma unroll
    for (int i = 0; i < 2; i++)
      af[i] = *reinterpret_cast<const short8*>(&As[(w * 32 + i * 16 + (lane & 15)) * 40 + koff]);
#pragma unroll
    for (int j = 0; j < 4; j++)
      bfr[j] = *reinterpret_cast<const short8*>(&Bs[(j * 16 + (lane & 15)) * 40 + koff]);
#pragma unroll
    for (int i = 0; i < 2; i++)
#pragma unroll
      for (int j = 0; j < 4; j++)
        acc[i][j] = __builtin_amdgcn_mfma_f32_16x16x32_bf16(af[i], bfr[j], acc[i][j], 0, 0, 0);
  }
  float t0 = temp[0];
#pragma unroll
  for (int i = 0; i < 2; i++) {
    int rbase = row0 + w * 32 + i * 16 + (lane >> 4) * 4;
#pragma unroll
    for (int j = 0; j < 4; j++) {
      int col = j * 16 + (lane & 15);
      if (col < COUT) {
        float bv = b2[col];
#pragma unroll
        for (int r = 0; r < 4; r++) {
          int row = rbase + r;
          if (row < NN) {
            float v = acc[i][j][r] + bv;
            X0B[(long)row * COUT + col] = f2bf(v);
            HIDB[(long)row * COUT + col] = t0 * v;
          }
        }
      }
    }
  }
}

// ---------------- propagation: bf16 features, 2 nodes/wave (half-wave per node) ----------------

__launch_bounds__(256)
__global__ void k_prop(const int* __restrict__ offs, const int* __restrict__ csrc,
                       const float* __restrict__ cnorm, const unsigned short* __restrict__ xin,
                       unsigned short* __restrict__ xout, float* __restrict__ hid,
                       const float* __restrict__ temp, int accidx) {
  int node = blockIdx.x * 8 + (threadIdx.x >> 5);
  if (node >= NN) return;
  int h = threadIdx.x & 31;
  int fp = h * 2;                 // feature pair (fp, fp+1)
  bool act = fp < COUT;           // lanes 0..24 of each half active
  int fc = act ? fp : 0;
  int s0 = offs[node], s1 = offs[node + 1];
  float a0 = 0.f, a1 = 0.f;
  int e = s0;
  for (; e + 3 < s1; e += 4) {
    int i0 = csrc[e], i1 = csrc[e + 1], i2 = csrc[e + 2], i3 = csrc[e + 3];
    float w0 = cnorm[e], w1 = cnorm[e + 1], w2 = cnorm[e + 2], w3 = cnorm[e + 3];
    unsigned v0 = *reinterpret_cast<const unsigned*>(&xin[(long)i0 * COUT + fc]);
    unsigned v1 = *reinterpret_cast<const unsigned*>(&xin[(long)i1 * COUT + fc]);
    unsigned v2 = *reinterpret_cast<const unsigned*>(&xin[(long)i2 * COUT + fc]);
    unsigned v3 = *reinterpret_cast<const unsigned*>(&xin[(long)i3 * COUT + fc]);
    a0 += w0 * __uint_as_float(v0 << 16) + w1 * __uint_as_float(v1 << 16)
        + w2 * __uint_as_float(v2 << 16) + w3 * __uint_as_float(v3 << 16);
    a1 += w0 * __uint_as_float(v0 & 0xffff0000u) + w1 * __uint_as_float(v1 & 0xffff0000u)
        + w2 * __uint_as_float(v2 & 0xffff0000u) + w3 * __uint_as_float(v3 & 0xffff0000u);
  }
  for (; e < s1; e++) {
    float w0 = cnorm[e];
    unsigned v0 = *reinterpret_cast<const unsigned*>(&xin[(long)csrc[e] * COUT + fc]);
    a0 += w0 * __uint_as_float(v0 << 16);
    a1 += w0 * __uint_as_float(v0 & 0xffff0000u);
  }
  if (act) {
    unsigned pk = ((unsigned)f2bf(a1) << 16) | (unsigned)f2bf(a0);
    *reinterpret_cast<unsigned*>(&xout[(long)node * COUT + fp]) = pk;
    if (accidx >= 0) {
      float t = temp[accidx];
      float2* hp = reinterpret_cast<float2*>(&hid[(long)node * COUT + fp]);
      float2 o = *hp;
      o.x += t * a0; o.y += t * a1;
      *hp = o;
    }
  }
}

// ---------------- log_softmax over 50 cols, one wave per row ----------------

__launch_bounds__(256)
__global__ void k_lsm(const float* __restrict__ hid, float* __restrict__ out) {
  int node = blockIdx.x * 4 + (threadIdx.x >> 6);
  if (node >= NN) return;
  int f = threadIdx.x & 63;
  float v = (f < COUT) ? hid[(long)node * COUT + f] : -INFINITY;
  float m = v;
#pragma unroll
  for (int o = 32; o > 0; o >>= 1) m = fmaxf(m, __shfl_xor(m, o, 64));
  float ex = (f < COUT) ? expf(v - m) : 0.f;
  float s = ex;
#pragma unroll
  for (int o = 32; o > 0; o >>= 1) s += __shfl_xor(s, o, 64);
  if (f < COUT) out[(long)node * COUT + f] = (v - m) - logf(s);
}

// ---------------- launch ----------------

extern "C" void kernel_launch(void* const* d_in, const int* in_sizes, int n_in,
                              void* d_out, int out_size, void* d_ws, size_t ws_size,
                              hipStream_t stream) {
  const float* X  = (const float*)d_in[0];
  const int* EI   = (const int*)d_in[1];
  const float* W1 = (const float*)d_in[2];
  const float* B1 = (const float*)d_in[3];
  const float* W2 = (const float*)d_in[4];
  const float* B2 = (const float*)d_in[5];
  const float* TEMP = (const float*)d_in[6];
  const int E = in_sizes[1] / 2;
  const int* src = EI;
  const int* dst = EI + E;

  char* ws = (char*)d_ws;
  size_t off = 0;
  auto alloc = [&](size_t bytes) -> void* {
    off = (off + 511) & ~(size_t)511;
    void* p = ws + off;
    off += bytes;
    return p;
  };
  unsigned short* HB  = (unsigned short*)alloc((size_t)NN * HID * 2);
  unsigned short* W1T = (unsigned short*)alloc((size_t)HID * KPAD * 2);
  unsigned short* W2T = (unsigned short*)alloc((size_t)NPADOUT * HID * 2);
  unsigned short* X0B = (unsigned short*)alloc((size_t)NN * COUT * 2);
  unsigned short* X1B = (unsigned short*)alloc((size_t)NN * COUT * 2);
  float* HIDB = (float*)alloc((size_t)NN * COUT * 4);
  float* DINV = (float*)alloc((size_t)NN * 4);
  int* DEG    = (int*)alloc((size_t)NN * 4);
  int* HIST   = (int*)alloc((size_t)NN * 4);
  int* CUR    = (int*)alloc((size_t)NN * 4);
  int* OFFS   = (int*)alloc((size_t)(NN + 1) * 4);
  int* INCL   = (int*)alloc((size_t)NN * 4);
  int* BSUM   = (int*)alloc(128 * 4);
  int* BPRE   = (int*)alloc(128 * 4);
  int* CSRC   = (int*)alloc((size_t)E * 4);
  float* CNORM = (float*)alloc((size_t)E * 4);

  hipMemsetAsync(DEG, 0, (size_t)NN * 4, stream);
  hipMemsetAsync(HIST, 0, (size_t)NN * 4, stream);
  hipMemsetAsync(CUR, 0, (size_t)NN * 4, stream);

  const int EB = (E + 255) / 256;
  const int NB1 = (NN + 255) / 256;
  const int NBS = (NN + 1023) / 1024;

  k_count<<<EB, 256, 0, stream>>>(src, dst, DEG, HIST, E);
  k_dinv<<<NB1, 256, 0, stream>>>(DEG, DINV, NN);
  k_scan_a<<<NBS, 256, 0, stream>>>(HIST, INCL, BSUM, NN);
  k_scan_b<<<1, 128, 0, stream>>>(BSUM, BPRE, NBS);
  k_scan_c<<<NB1, 256, 0, stream>>>(INCL, BPRE, OFFS, NN);
  k_scatter<<<EB, 256, 0, stream>>>(src, dst, DINV, OFFS, CUR, CSRC, CNORM, E);

  k_w1t<<<(HID * KPAD + 255) / 256, 256, 0, stream>>>(W1, W1T);
  k_w2t<<<(NPADOUT * HID + 255) / 256, 256, 0, stream>>>(W2, W2T);

  k_gemm1<<<(NN + 127) / 128, 512, 0, stream>>>(X, W1T, B1, HB);
  k_gemm2<<<(NN + 127) / 128, 256, 0, stream>>>(HB, W2T, B2, TEMP, X0B, HIDB);

  const int PB = (NN + 7) / 8;
  for (int k = 0; k < 5; k++) {
    k_prop<<<PB, 256, 0, stream>>>(OFFS, CSRC, CNORM, X0B, X1B, HIDB, TEMP, -1);
    k_prop<<<PB, 256, 0, stream>>>(OFFS, CSRC, CNORM, X1B, X0B, HIDB, TEMP, k + 1);
  }
  k_lsm<<<(NN + 3) / 4, 256, 0, stream>>>(HIDB, (float*)d_out);
}

// Round 3
// 976.922 us; speedup vs baseline: 1.4459x; 1.1027x over previous
//
#include <hip/hip_runtime.h>

#define NN 100000
#define CIN 500
#define KPAD 512
#define HID 256
#define COUT 50
#define NPADOUT 64

#define NBLK 256                       // edge-chunk blocks for P1/P2
#define CB 128                         // nodes per coarse bucket
#define NC ((NN + CB - 1) / CB)        // 782 coarse buckets
#define NCB (NC * NBLK)                // 200192 per-(bucket,block) counts
#define NCB2 (2 * NCB)                 // dst + src parts

typedef __attribute__((ext_vector_type(8))) short short8;
typedef __attribute__((ext_vector_type(4))) float f32x4;

static __device__ __forceinline__ unsigned short f2bf(float f) {
  union { float f; unsigned u; } v; v.f = f;
  unsigned r = (v.u + 0x7fffu + ((v.u >> 16) & 1u)) >> 16;
  return (unsigned short)r;
}

// ---------------- build P1: coarse histograms (src & dst), LDS-privatized ----------------

__launch_bounds__(256)
__global__ void k_p1(const int* __restrict__ src, const int* __restrict__ dst,
                     int* __restrict__ blk_cnt, int E, int chunk) {
  __shared__ int bd[NC], bs[NC];
  int tid = threadIdx.x;
  for (int i = tid; i < NC; i += 256) { bd[i] = 0; bs[i] = 0; }
  __syncthreads();
  int e0 = blockIdx.x * chunk, e1 = min(E, e0 + chunk);
  for (int e = e0 + tid; e < e1; e += 256) {
    atomicAdd(&bd[dst[e] >> 7], 1);
    atomicAdd(&bs[src[e] >> 7], 1);
  }
  __syncthreads();
  for (int i = tid; i < NC; i += 256) {
    blk_cnt[i * NBLK + blockIdx.x] = bd[i];            // bucket-major, dst part
    blk_cnt[NCB + i * NBLK + blockIdx.x] = bs[i];      // src part
  }
}

// ---------------- scan over NCB2 counts -> exclusive slot bases ----------------

__global__ void k_scan_a(const int* __restrict__ hist, int* __restrict__ incl,
                         int* __restrict__ bsum, int n) {
  __shared__ int ts[256];
  int tid = threadIdx.x;
  int base = blockIdx.x * 1024 + tid * 4;
  int a0 = 0, a1 = 0, a2 = 0, a3 = 0;
  if (base + 3 < n) {
    a0 = hist[base]; a1 = hist[base + 1]; a2 = hist[base + 2]; a3 = hist[base + 3];
  } else {
    if (base     < n) a0 = hist[base];
    if (base + 1 < n) a1 = hist[base + 1];
    if (base + 2 < n) a2 = hist[base + 2];
    if (base + 3 < n) a3 = hist[base + 3];
  }
  a1 += a0; a2 += a1; a3 += a2;
  ts[tid] = a3;
  __syncthreads();
  for (int o = 1; o < 256; o <<= 1) {
    int v = ts[tid];
    if (tid >= o) v += ts[tid - o];
    __syncthreads();
    ts[tid] = v;
    __syncthreads();
  }
  int ex = tid ? ts[tid - 1] : 0;
  if (base     < n) incl[base]     = a0 + ex;
  if (base + 1 < n) incl[base + 1] = a1 + ex;
  if (base + 2 < n) incl[base + 2] = a2 + ex;
  if (base + 3 < n) incl[base + 3] = a3 + ex;
  if (tid == 255) bsum[blockIdx.x] = ts[255];
}

__global__ void k_scan_b(const int* __restrict__ bsum, int* __restrict__ bpre, int nb) {
  __shared__ int s[512];
  int tid = threadIdx.x;
  s[tid] = (tid < nb) ? bsum[tid] : 0;
  __syncthreads();
  for (int o = 1; o < 512; o <<= 1) {
    int v = s[tid];
    if (tid >= o) v += s[tid - o];
    __syncthreads();
    s[tid] = v;
    __syncthreads();
  }
  if (tid < nb) bpre[tid] = tid ? s[tid - 1] : 0;
}

__global__ void k_scan_c(const int* __restrict__ incl, const int* __restrict__ bpre,
                         int* __restrict__ slot, int n) {
  int g = blockIdx.x * 256 + threadIdx.x;
  if (g < n) {
    slot[g + 1] = incl[g] + bpre[g >> 10];
    if (g == 0) slot[0] = 0;
  }
}

// ---------------- build P2: scatter edges into coarse buckets (no global atomics) ----------------

__launch_bounds__(256)
__global__ void k_p2(const int* __restrict__ src, const int* __restrict__ dst,
                     const int* __restrict__ slot, int* __restrict__ pkd,
                     unsigned char* __restrict__ pks, int E, int chunk) {
  __shared__ int cd[NC], cs[NC];
  int tid = threadIdx.x;
  for (int i = tid; i < NC; i += 256) {
    cd[i] = slot[i * NBLK + blockIdx.x];
    cs[i] = slot[NCB + i * NBLK + blockIdx.x] - E;
  }
  __syncthreads();
  int e0 = blockIdx.x * chunk, e1 = min(E, e0 + chunk);
  for (int e = e0 + tid; e < e1; e += 256) {
    int s = src[e], d = dst[e];
    int pd = atomicAdd(&cd[d >> 7], 1);
    pkd[pd] = (s << 7) | (d & 127);
    int ps = atomicAdd(&cs[s >> 7], 1);
    pks[ps] = (unsigned char)(s & 127);
  }
}

// ---------------- build P3s: fine histogram of src -> dinv ----------------

__launch_bounds__(256)
__global__ void k_p3s(const int* __restrict__ slot, const unsigned char* __restrict__ pks,
                      float* __restrict__ dinv, int E) {
  __shared__ int hist[CB];
  int b = blockIdx.x, tid = threadIdx.x;
  if (tid < CB) hist[tid] = 0;
  __syncthreads();
  int s0 = slot[NCB + b * NBLK] - E;
  int s1 = slot[NCB + (b + 1) * NBLK] - E;
  for (int e = s0 + tid; e < s1; e += 256) atomicAdd(&hist[pks[e]], 1);
  __syncthreads();
  if (tid < CB) {
    int node = b * CB + tid;
    if (node < NN) {
      int c = hist[tid];
      dinv[node] = c > 0 ? rsqrtf((float)c) : 0.f;
    }
  }
}

// ---------------- build P3d: fine sort by dst -> offs + interleaved (src,norm) CSR ----------------

__launch_bounds__(256)
__global__ void k_p3d(const int* __restrict__ slot, const int* __restrict__ pkd,
                      const float* __restrict__ dinv, int* __restrict__ offs,
                      int2* __restrict__ epk, int E) {
  __shared__ int hist[CB], base[CB], cur[CB];
  int b = blockIdx.x, tid = threadIdx.x;
  if (tid < CB) hist[tid] = 0;
  __syncthreads();
  int s0 = slot[b * NBLK];
  int s1 = slot[(b + 1) * NBLK];
  for (int e = s0 + tid; e < s1; e += 256) atomicAdd(&hist[pkd[e] & 127], 1);
  __syncthreads();
  if (tid == 0) {
    int acc = s0;
    for (int i = 0; i < CB; i++) { base[i] = acc; cur[i] = acc; acc += hist[i]; }
  }
  __syncthreads();
  if (tid < CB) {
    int node = b * CB + tid;
    if (node < NN) offs[node] = base[tid];
  }
  if (b == gridDim.x - 1 && tid == 0) offs[NN] = E;
  for (int e = s0 + tid; e < s1; e += 256) {
    int pk = pkd[e];
    int fine = pk & 127, s = pk >> 7;
    int pos = atomicAdd(&cur[fine], 1);
    float nm = dinv[s] * dinv[b * CB + fine];
    epk[pos] = make_int2(s, __float_as_int(nm));
  }
}

// ---------------- weight transpose+convert ----------------

__global__ void k_w1t(const float* __restrict__ W1, unsigned short* __restrict__ W1T) {
  int idx = blockIdx.x * 256 + threadIdx.x;
  if (idx < HID * KPAD) {
    int n = idx >> 9, k = idx & 511;
    W1T[idx] = (k < CIN) ? f2bf(W1[(long)k * HID + n]) : (unsigned short)0;
  }
}

__global__ void k_w2t(const float* __restrict__ W2, unsigned short* __restrict__ W2T) {
  int idx = blockIdx.x * 256 + threadIdx.x;
  if (idx < NPADOUT * HID) {
    int n = idx >> 8, k = idx & 255;
    W2T[idx] = (n < COUT) ? f2bf(W2[(long)k * COUT + n]) : (unsigned short)0;
  }
}

// ---------------- GEMM1: 128x256 tile per block, 512 thr ----------------

__launch_bounds__(512)
__global__ void k_gemm1(const float* __restrict__ X, const unsigned short* __restrict__ W1T,
                        const float* __restrict__ b1, unsigned short* __restrict__ HB) {
  __shared__ unsigned short As[128 * 40];
  __shared__ unsigned short Bs[256 * 40];
  const int tid = threadIdx.x;
  const int lane = tid & 63, w = tid >> 6;
  const int wr = w >> 2, wc = w & 3;
  const int row0 = blockIdx.x * 128;
  f32x4 acc[4][4] = {};
  const int sr = tid >> 3, sc = tid & 7;
  const int br = tid >> 2, bc = tid & 3;

  for (int kk = 0; kk < KPAD; kk += 32) {
    __syncthreads();
#pragma unroll
    for (int p = 0; p < 2; p++) {
      int r = sr + p * 64;
      int grow = row0 + r;
      int gk = kk + sc * 4;
      ushort4 val;
      if (grow < NN && gk < CIN) {
        const float4 f = *reinterpret_cast<const float4*>(&X[(long)grow * CIN + gk]);
        val.x = f2bf(f.x); val.y = f2bf(f.y); val.z = f2bf(f.z); val.w = f2bf(f.w);
      } else {
        val.x = val.y = val.z = val.w = 0;
      }
      *reinterpret_cast<ushort4*>(&As[r * 40 + sc * 4]) = val;
    }
#pragma unroll
    for (int p = 0; p < 2; p++) {
      int nl = br + p * 128;
      const uint4 v = *reinterpret_cast<const uint4*>(&W1T[(long)nl * KPAD + kk + bc * 8]);
      *reinterpret_cast<uint4*>(&Bs[nl * 40 + bc * 8]) = v;
    }
    __syncthreads();
    short8 af[4], bfr[4];
    const int koff = (lane >> 4) * 8;
#pragma unroll
    for (int i = 0; i < 4; i++)
      af[i] = *reinterpret_cast<const short8*>(&As[(wr * 64 + i * 16 + (lane & 15)) * 40 + koff]);
#pragma unroll
    for (int j = 0; j < 4; j++)
      bfr[j] = *reinterpret_cast<const short8*>(&Bs[(wc * 64 + j * 16 + (lane & 15)) * 40 + koff]);
#pragma unroll
    for (int i = 0; i < 4; i++)
#pragma unroll
      for (int j = 0; j < 4; j++)
        acc[i][j] = __builtin_amdgcn_mfma_f32_16x16x32_bf16(af[i], bfr[j], acc[i][j], 0, 0, 0);
  }
#pragma unroll
  for (int i = 0; i < 4; i++) {
    int rbase = row0 + wr * 64 + i * 16 + (lane >> 4) * 4;
#pragma unroll
    for (int j = 0; j < 4; j++) {
      int col = wc * 64 + j * 16 + (lane & 15);
      float bv = b1[col];
#pragma unroll
      for (int r = 0; r < 4; r++) {
        int row = rbase + r;
        if (row < NN) {
          float v = acc[i][j][r] + bv;
          v = v > 0.f ? v : 0.f;
          HB[(long)row * HID + col] = f2bf(v);
        }
      }
    }
  }
}

// ---------------- GEMM2 ----------------

__launch_bounds__(256)
__global__ void k_gemm2(const unsigned short* __restrict__ HB, const unsigned short* __restrict__ W2T,
                        const float* __restrict__ b2, const float* __restrict__ temp,
                        unsigned short* __restrict__ X0B, float* __restrict__ HIDB) {
  __shared__ unsigned short As[128 * 40];
  __shared__ unsigned short Bs[64 * 40];
  const int tid = threadIdx.x;
  const int lane = tid & 63, w = tid >> 6;
  const int row0 = blockIdx.x * 128;
  f32x4 acc[2][4] = {};
  const int ar = tid >> 2, ac = tid & 3;

  for (int kk = 0; kk < HID; kk += 32) {
    __syncthreads();
#pragma unroll
    for (int p = 0; p < 2; p++) {
      int r = ar + p * 64;
      int grow = row0 + r;
      uint4 v;
      if (grow < NN) v = *reinterpret_cast<const uint4*>(&HB[(long)grow * HID + kk + ac * 8]);
      else { v.x = v.y = v.z = v.w = 0; }
      *reinterpret_cast<uint4*>(&As[r * 40 + ac * 8]) = v;
    }
    {
      int nl = tid >> 2, c = tid & 3;
      const uint4 v = *reinterpret_cast<const uint4*>(&W2T[nl * HID + kk + c * 8]);
      *reinterpret_cast<uint4*>(&Bs[nl * 40 + c * 8]) = v;
    }
    __syncthreads();
    short8 af[2], bfr[4];
    const int koff = (lane >> 4) * 8;
#pragma unroll
    for (int i = 0; i < 2; i++)
      af[i] = *reinterpret_cast<const short8*>(&As[(w * 32 + i * 16 + (lane & 15)) * 40 + koff]);
#pragma unroll
    for (int j = 0; j < 4; j++)
      bfr[j] = *reinterpret_cast<const short8*>(&Bs[(j * 16 + (lane & 15)) * 40 + koff]);
#pragma unroll
    for (int i = 0; i < 2; i++)
#pragma unroll
      for (int j = 0; j < 4; j++)
        acc[i][j] = __builtin_amdgcn_mfma_f32_16x16x32_bf16(af[i], bfr[j], acc[i][j], 0, 0, 0);
  }
  float t0 = temp[0];
#pragma unroll
  for (int i = 0; i < 2; i++) {
    int rbase = row0 + w * 32 + i * 16 + (lane >> 4) * 4;
#pragma unroll
    for (int j = 0; j < 4; j++) {
      int col = j * 16 + (lane & 15);
      if (col < COUT) {
        float bv = b2[col];
#pragma unroll
        for (int r = 0; r < 4; r++) {
          int row = rbase + r;
          if (row < NN) {
            float v = acc[i][j][r] + bv;
            X0B[(long)row * COUT + col] = f2bf(v);
            HIDB[(long)row * COUT + col] = t0 * v;
          }
        }
      }
    }
  }
}

// ---------------- propagation: bf16 features, 2 nodes/wave, interleaved (src,norm) ----------------

__launch_bounds__(256)
__global__ void k_prop(const int* __restrict__ offs, const int2* __restrict__ epk,
                       const unsigned short* __restrict__ xin,
                       unsigned short* __restrict__ xout, float* __restrict__ hid,
                       const float* __restrict__ temp, int accidx) {
  int node = blockIdx.x * 8 + (threadIdx.x >> 5);
  if (node >= NN) return;
  int h = threadIdx.x & 31;
  int fp = h * 2;
  bool act = fp < COUT;
  int fc = act ? fp : 0;
  int s0 = offs[node], s1 = offs[node + 1];
  float a0 = 0.f, a1 = 0.f;
  int e = s0;
  for (; e + 3 < s1; e += 4) {
    int2 p0 = epk[e], p1 = epk[e + 1], p2 = epk[e + 2], p3 = epk[e + 3];
    unsigned v0 = *reinterpret_cast<const unsigned*>(&xin[(long)p0.x * COUT + fc]);
    unsigned v1 = *reinterpret_cast<const unsigned*>(&xin[(long)p1.x * COUT + fc]);
    unsigned v2 = *reinterpret_cast<const unsigned*>(&xin[(long)p2.x * COUT + fc]);
    unsigned v3 = *reinterpret_cast<const unsigned*>(&xin[(long)p3.x * COUT + fc]);
    float w0 = __int_as_float(p0.y), w1 = __int_as_float(p1.y);
    float w2 = __int_as_float(p2.y), w3 = __int_as_float(p3.y);
    a0 += w0 * __uint_as_float(v0 << 16) + w1 * __uint_as_float(v1 << 16)
        + w2 * __uint_as_float(v2 << 16) + w3 * __uint_as_float(v3 << 16);
    a1 += w0 * __uint_as_float(v0 & 0xffff0000u) + w1 * __uint_as_float(v1 & 0xffff0000u)
        + w2 * __uint_as_float(v2 & 0xffff0000u) + w3 * __uint_as_float(v3 & 0xffff0000u);
  }
  for (; e < s1; e++) {
    int2 p0 = epk[e];
    float w0 = __int_as_float(p0.y);
    unsigned v0 = *reinterpret_cast<const unsigned*>(&xin[(long)p0.x * COUT + fc]);
    a0 += w0 * __uint_as_float(v0 << 16);
    a1 += w0 * __uint_as_float(v0 & 0xffff0000u);
  }
  if (act) {
    unsigned pk = ((unsigned)f2bf(a1) << 16) | (unsigned)f2bf(a0);
    *reinterpret_cast<unsigned*>(&xout[(long)node * COUT + fp]) = pk;
    if (accidx >= 0) {
      float t = temp[accidx];
      float2* hp = reinterpret_cast<float2*>(&hid[(long)node * COUT + fp]);
      float2 o = *hp;
      o.x += t * a0; o.y += t * a1;
      *hp = o;
    }
  }
}

// ---------------- log_softmax ----------------

__launch_bounds__(256)
__global__ void k_lsm(const float* __restrict__ hid, float* __restrict__ out) {
  int node = blockIdx.x * 4 + (threadIdx.x >> 6);
  if (node >= NN) return;
  int f = threadIdx.x & 63;
  float v = (f < COUT) ? hid[(long)node * COUT + f] : -INFINITY;
  float m = v;
#pragma unroll
  for (int o = 32; o > 0; o >>= 1) m = fmaxf(m, __shfl_xor(m, o, 64));
  float ex = (f < COUT) ? expf(v - m) : 0.f;
  float s = ex;
#pragma unroll
  for (int o = 32; o > 0; o >>= 1) s += __shfl_xor(s, o, 64);
  if (f < COUT) out[(long)node * COUT + f] = (v - m) - logf(s);
}

// ---------------- launch ----------------

extern "C" void kernel_launch(void* const* d_in, const int* in_sizes, int n_in,
                              void* d_out, int out_size, void* d_ws, size_t ws_size,
                              hipStream_t stream) {
  const float* X  = (const float*)d_in[0];
  const int* EI   = (const int*)d_in[1];
  const float* W1 = (const float*)d_in[2];
  const float* B1 = (const float*)d_in[3];
  const float* W2 = (const float*)d_in[4];
  const float* B2 = (const float*)d_in[5];
  const float* TEMP = (const float*)d_in[6];
  const int E = in_sizes[1] / 2;
  const int* src = EI;
  const int* dst = EI + E;

  char* ws = (char*)d_ws;
  size_t off = 0;
  auto alloc = [&](size_t bytes) -> void* {
    off = (off + 511) & ~(size_t)511;
    void* p = ws + off;
    off += bytes;
    return p;
  };
  unsigned short* HB  = (unsigned short*)alloc((size_t)NN * HID * 2);
  unsigned short* W1T = (unsigned short*)alloc((size_t)HID * KPAD * 2);
  unsigned short* W2T = (unsigned short*)alloc((size_t)NPADOUT * HID * 2);
  unsigned short* X0B = (unsigned short*)alloc((size_t)NN * COUT * 2);
  unsigned short* X1B = (unsigned short*)alloc((size_t)NN * COUT * 2);
  float* HIDB = (float*)alloc((size_t)NN * COUT * 4);
  float* DINV = (float*)alloc((size_t)NN * 4);
  int* OFFS   = (int*)alloc((size_t)(NN + 1) * 4);
  int* BLKC   = (int*)alloc((size_t)NCB2 * 4);
  int* INCL   = (int*)alloc((size_t)NCB2 * 4);
  int* SLOT   = (int*)alloc((size_t)(NCB2 + 1) * 4);
  int* BSUM   = (int*)alloc(512 * 4);
  int* BPRE   = (int*)alloc(512 * 4);
  int* PKD    = (int*)alloc((size_t)E * 4);
  unsigned char* PKS = (unsigned char*)alloc((size_t)E);
  int2* EPK   = (int2*)alloc((size_t)E * 8);

  const int chunk = (E + NBLK - 1) / NBLK;
  const int nscan = NCB2;
  const int nsa = (nscan + 1023) / 1024;   // 391 scan_a blocks

  k_p1<<<NBLK, 256, 0, stream>>>(src, dst, BLKC, E, chunk);
  k_scan_a<<<nsa, 256, 0, stream>>>(BLKC, INCL, BSUM, nscan);
  k_scan_b<<<1, 512, 0, stream>>>(BSUM, BPRE, nsa);
  k_scan_c<<<(nscan + 255) / 256, 256, 0, stream>>>(INCL, BPRE, SLOT, nscan);
  k_p2<<<NBLK, 256, 0, stream>>>(src, dst, SLOT, PKD, PKS, E, chunk);
  k_p3s<<<NC, 256, 0, stream>>>(SLOT, PKS, DINV, E);
  k_p3d<<<NC, 256, 0, stream>>>(SLOT, PKD, DINV, OFFS, EPK, E);

  k_w1t<<<(HID * KPAD + 255) / 256, 256, 0, stream>>>(W1, W1T);
  k_w2t<<<(NPADOUT * HID + 255) / 256, 256, 0, stream>>>(W2, W2T);

  k_gemm1<<<(NN + 127) / 128, 512, 0, stream>>>(X, W1T, B1, HB);
  k_gemm2<<<(NN + 127) / 128, 256, 0, stream>>>(HB, W2T, B2, TEMP, X0B, HIDB);

  const int PB = (NN + 7) / 8;
  for (int k = 0; k < 5; k++) {
    k_prop<<<PB, 256, 0, stream>>>(OFFS, EPK, X0B, X1B, HIDB, TEMP, -1);
    k_prop<<<PB, 256, 0, stream>>>(OFFS, EPK, X1B, X0B, HIDB, TEMP, k + 1);
  }
  k_lsm<<<(NN + 3) / 4, 256, 0, stream>>>(HIDB, (float*)d_out);
}

// Round 4
// 974.126 us; speedup vs baseline: 1.4500x; 1.0029x over previous
//
#include <hip/hip_runtime.h>

#define NN 100000
#define CIN 500
#define KPAD 512
#define HID 256
#define COUT 50
#define NPADOUT 64
#define FPAD 64                        // padded feature-row length for x_k (128 B)

#define NBLK 256                       // edge-chunk blocks for P1/P2
#define CB 128                         // nodes per coarse bucket
#define NC ((NN + CB - 1) / CB)        // 782 coarse buckets
#define NCB (NC * NBLK)                // per-(bucket,block) counts
#define NCB2 (2 * NCB)                 // dst + src parts

typedef __attribute__((ext_vector_type(8))) short short8;
typedef __attribute__((ext_vector_type(4))) float f32x4;

static __device__ __forceinline__ unsigned short f2bf(float f) {
  union { float f; unsigned u; } v; v.f = f;
  unsigned r = (v.u + 0x7fffu + ((v.u >> 16) & 1u)) >> 16;
  return (unsigned short)r;
}

// ---------------- build P1: coarse histograms (src & dst), LDS-privatized ----------------

__launch_bounds__(256)
__global__ void k_p1(const int* __restrict__ src, const int* __restrict__ dst,
                     int* __restrict__ blk_cnt, int E, int chunk) {
  __shared__ int bd[NC], bs[NC];
  int tid = threadIdx.x;
  for (int i = tid; i < NC; i += 256) { bd[i] = 0; bs[i] = 0; }
  __syncthreads();
  int e0 = blockIdx.x * chunk, e1 = min(E, e0 + chunk);
  for (int e = e0 + tid; e < e1; e += 256) {
    atomicAdd(&bd[dst[e] >> 7], 1);
    atomicAdd(&bs[src[e] >> 7], 1);
  }
  __syncthreads();
  for (int i = tid; i < NC; i += 256) {
    blk_cnt[i * NBLK + blockIdx.x] = bd[i];
    blk_cnt[NCB + i * NBLK + blockIdx.x] = bs[i];
  }
}

// ---------------- scan over NCB2 counts -> exclusive slot bases ----------------

__global__ void k_scan_a(const int* __restrict__ hist, int* __restrict__ incl,
                         int* __restrict__ bsum, int n) {
  __shared__ int ts[256];
  int tid = threadIdx.x;
  int base = blockIdx.x * 1024 + tid * 4;
  int a0 = 0, a1 = 0, a2 = 0, a3 = 0;
  if (base + 3 < n) {
    a0 = hist[base]; a1 = hist[base + 1]; a2 = hist[base + 2]; a3 = hist[base + 3];
  } else {
    if (base     < n) a0 = hist[base];
    if (base + 1 < n) a1 = hist[base + 1];
    if (base + 2 < n) a2 = hist[base + 2];
    if (base + 3 < n) a3 = hist[base + 3];
  }
  a1 += a0; a2 += a1; a3 += a2;
  ts[tid] = a3;
  __syncthreads();
  for (int o = 1; o < 256; o <<= 1) {
    int v = ts[tid];
    if (tid >= o) v += ts[tid - o];
    __syncthreads();
    ts[tid] = v;
    __syncthreads();
  }
  int ex = tid ? ts[tid - 1] : 0;
  if (base     < n) incl[base]     = a0 + ex;
  if (base + 1 < n) incl[base + 1] = a1 + ex;
  if (base + 2 < n) incl[base + 2] = a2 + ex;
  if (base + 3 < n) incl[base + 3] = a3 + ex;
  if (tid == 255) bsum[blockIdx.x] = ts[255];
}

__global__ void k_scan_b(const int* __restrict__ bsum, int* __restrict__ bpre, int nb) {
  __shared__ int s[512];
  int tid = threadIdx.x;
  s[tid] = (tid < nb) ? bsum[tid] : 0;
  __syncthreads();
  for (int o = 1; o < 512; o <<= 1) {
    int v = s[tid];
    if (tid >= o) v += s[tid - o];
    __syncthreads();
    s[tid] = v;
    __syncthreads();
  }
  if (tid < nb) bpre[tid] = tid ? s[tid - 1] : 0;
}

__global__ void k_scan_c(const int* __restrict__ incl, const int* __restrict__ bpre,
                         int* __restrict__ slot, int n) {
  int g = blockIdx.x * 256 + threadIdx.x;
  if (g < n) {
    slot[g + 1] = incl[g] + bpre[g >> 10];
    if (g == 0) slot[0] = 0;
  }
}

// ---------------- build P2: scatter edges into coarse buckets (no global atomics) ----------------

__launch_bounds__(256)
__global__ void k_p2(const int* __restrict__ src, const int* __restrict__ dst,
                     const int* __restrict__ slot, int* __restrict__ pkd,
                     unsigned char* __restrict__ pks, int E, int chunk) {
  __shared__ int cd[NC], cs[NC];
  int tid = threadIdx.x;
  for (int i = tid; i < NC; i += 256) {
    cd[i] = slot[i * NBLK + blockIdx.x];
    cs[i] = slot[NCB + i * NBLK + blockIdx.x] - E;
  }
  __syncthreads();
  int e0 = blockIdx.x * chunk, e1 = min(E, e0 + chunk);
  for (int e = e0 + tid; e < e1; e += 256) {
    int s = src[e], d = dst[e];
    int pd = atomicAdd(&cd[d >> 7], 1);
    pkd[pd] = (s << 7) | (d & 127);
    int ps = atomicAdd(&cs[s >> 7], 1);
    pks[ps] = (unsigned char)(s & 127);
  }
}

// ---------------- build P3s: fine histogram of src -> dinv ----------------

__launch_bounds__(256)
__global__ void k_p3s(const int* __restrict__ slot, const unsigned char* __restrict__ pks,
                      float* __restrict__ dinv, int E) {
  __shared__ int hist[CB];
  int b = blockIdx.x, tid = threadIdx.x;
  if (tid < CB) hist[tid] = 0;
  __syncthreads();
  int s0 = slot[NCB + b * NBLK] - E;
  int s1 = slot[NCB + (b + 1) * NBLK] - E;
  for (int e = s0 + tid; e < s1; e += 256) atomicAdd(&hist[pks[e]], 1);
  __syncthreads();
  if (tid < CB) {
    int node = b * CB + tid;
    if (node < NN) {
      int c = hist[tid];
      dinv[node] = c > 0 ? rsqrtf((float)c) : 0.f;
    }
  }
}

// ---------------- build P3d: fine sort by dst -> offs + interleaved (src,norm) CSR ----------------

__launch_bounds__(256)
__global__ void k_p3d(const int* __restrict__ slot, const int* __restrict__ pkd,
                      const float* __restrict__ dinv, int* __restrict__ offs,
                      int2* __restrict__ epk, int E) {
  __shared__ int hist[CB], base[CB], cur[CB];
  int b = blockIdx.x, tid = threadIdx.x;
  if (tid < CB) hist[tid] = 0;
  __syncthreads();
  int s0 = slot[b * NBLK];
  int s1 = slot[(b + 1) * NBLK];
  for (int e = s0 + tid; e < s1; e += 256) atomicAdd(&hist[pkd[e] & 127], 1);
  __syncthreads();
  if (tid == 0) {
    int acc = s0;
    for (int i = 0; i < CB; i++) { base[i] = acc; cur[i] = acc; acc += hist[i]; }
  }
  __syncthreads();
  if (tid < CB) {
    int node = b * CB + tid;
    if (node < NN) offs[node] = base[tid];
  }
  if (b == gridDim.x - 1 && tid == 0) offs[NN] = E;
  for (int e = s0 + tid; e < s1; e += 256) {
    int pk = pkd[e];
    int fine = pk & 127, s = pk >> 7;
    int pos = atomicAdd(&cur[fine], 1);
    float nm = dinv[s] * dinv[b * CB + fine];
    epk[pos] = make_int2(s, __float_as_int(nm));
  }
}

// ---------------- weight transpose+convert (merged) ----------------

__global__ void k_wt(const float* __restrict__ W1, const float* __restrict__ W2,
                     unsigned short* __restrict__ W1T, unsigned short* __restrict__ W2T) {
  int idx = blockIdx.x * 256 + threadIdx.x;
  if (idx < HID * KPAD) {
    int n = idx >> 9, k = idx & 511;
    W1T[idx] = (k < CIN) ? f2bf(W1[(long)k * HID + n]) : (unsigned short)0;
  } else if (idx < HID * KPAD + NPADOUT * HID) {
    int i2 = idx - HID * KPAD;
    int n = i2 >> 8, k = i2 & 255;
    W2T[i2] = (n < COUT) ? f2bf(W2[(long)k * COUT + n]) : (unsigned short)0;
  }
}

// ---------------- GEMM1: 128x256 tile, register-prefetch pipelined K-loop ----------------

__launch_bounds__(512)
__global__ void k_gemm1(const float* __restrict__ X, const unsigned short* __restrict__ W1T,
                        const float* __restrict__ b1, unsigned short* __restrict__ HB) {
  __shared__ unsigned short As[128 * 40];
  __shared__ unsigned short Bs[256 * 40];
  const int tid = threadIdx.x;
  const int lane = tid & 63, w = tid >> 6;
  const int wr = w >> 2, wc = w & 3;
  const int row0 = blockIdx.x * 128;
  f32x4 acc[4][4] = {};
  const int sr = tid >> 3, sc = tid & 7;
  const int br = tid >> 2, bc = tid & 3;

  float4 ra[2];
  uint4 rb[2];
  // initial load (kk=0; sc*4 <= 28 < CIN, no k-bound needed)
#pragma unroll
  for (int p = 0; p < 2; p++) {
    int grow = row0 + sr + p * 64;
    int gr = grow < NN ? grow : NN - 1;
    float4 f = *reinterpret_cast<const float4*>(&X[(long)gr * CIN + sc * 4]);
    if (grow >= NN) { f.x = 0.f; f.y = 0.f; f.z = 0.f; f.w = 0.f; }
    ra[p] = f;
    rb[p] = *reinterpret_cast<const uint4*>(&W1T[(long)(br + p * 128) * KPAD + bc * 8]);
  }

  for (int ks = 0; ks < 16; ks++) {
    const int kk = ks * 32;
    // stage current regs -> LDS (convert A fp32 -> bf16)
#pragma unroll
    for (int p = 0; p < 2; p++) {
      ushort4 val;
      val.x = f2bf(ra[p].x); val.y = f2bf(ra[p].y);
      val.z = f2bf(ra[p].z); val.w = f2bf(ra[p].w);
      *reinterpret_cast<ushort4*>(&As[(sr + p * 64) * 40 + sc * 4]) = val;
      *reinterpret_cast<uint4*>(&Bs[(br + p * 128) * 40 + bc * 8]) = rb[p];
    }
    // prefetch next K-step into registers (overlaps with MFMA below)
    if (ks < 15) {
      const int nk = kk + 32;
      const int gk = nk + sc * 4;
      const bool kok = gk < CIN;
      const int gkc = kok ? gk : 0;
#pragma unroll
      for (int p = 0; p < 2; p++) {
        int grow = row0 + sr + p * 64;
        int gr = grow < NN ? grow : NN - 1;
        float4 f = *reinterpret_cast<const float4*>(&X[(long)gr * CIN + gkc]);
        if (grow >= NN || !kok) { f.x = 0.f; f.y = 0.f; f.z = 0.f; f.w = 0.f; }
        ra[p] = f;
        rb[p] = *reinterpret_cast<const uint4*>(&W1T[(long)(br + p * 128) * KPAD + nk + bc * 8]);
      }
    }
    __syncthreads();
    short8 af[4], bfr[4];
    const int koff = (lane >> 4) * 8;
#pragma unroll
    for (int i = 0; i < 4; i++)
      af[i] = *reinterpret_cast<const short8*>(&As[(wr * 64 + i * 16 + (lane & 15)) * 40 + koff]);
#pragma unroll
    for (int j = 0; j < 4; j++)
      bfr[j] = *reinterpret_cast<const short8*>(&Bs[(wc * 64 + j * 16 + (lane & 15)) * 40 + koff]);
#pragma unroll
    for (int i = 0; i < 4; i++)
#pragma unroll
      for (int j = 0; j < 4; j++)
        acc[i][j] = __builtin_amdgcn_mfma_f32_16x16x32_bf16(af[i], bfr[j], acc[i][j], 0, 0, 0);
    __syncthreads();
  }
#pragma unroll
  for (int i = 0; i < 4; i++) {
    int rbase = row0 + wr * 64 + i * 16 + (lane >> 4) * 4;
#pragma unroll
    for (int j = 0; j < 4; j++) {
      int col = wc * 64 + j * 16 + (lane & 15);
      float bv = b1[col];
#pragma unroll
      for (int r = 0; r < 4; r++) {
        int row = rbase + r;
        if (row < NN) {
          float v = acc[i][j][r] + bv;
          v = v > 0.f ? v : 0.f;
          HB[(long)row * HID + col] = f2bf(v);
        }
      }
    }
  }
}

// ---------------- GEMM2: writes x0 (bf16, FPAD-padded rows) and hid = temp[0]*x0 ----------------

__launch_bounds__(256)
__global__ void k_gemm2(const unsigned short* __restrict__ HB, const unsigned short* __restrict__ W2T,
                        const float* __restrict__ b2, const float* __restrict__ temp,
                        unsigned short* __restrict__ X0B, float* __restrict__ HIDB) {
  __shared__ unsigned short As[128 * 40];
  __shared__ unsigned short Bs[64 * 40];
  const int tid = threadIdx.x;
  const int lane = tid & 63, w = tid >> 6;
  const int row0 = blockIdx.x * 128;
  f32x4 acc[2][4] = {};
  const int ar = tid >> 2, ac = tid & 3;

  for (int kk = 0; kk < HID; kk += 32) {
    __syncthreads();
#pragma unroll
    for (int p = 0; p < 2; p++) {
      int r = ar + p * 64;
      int grow = row0 + r;
      uint4 v;
      if (grow < NN) v = *reinterpret_cast<const uint4*>(&HB[(long)grow * HID + kk + ac * 8]);
      else { v.x = v.y = v.z = v.w = 0; }
      *reinterpret_cast<uint4*>(&As[r * 40 + ac * 8]) = v;
    }
    {
      int nl = tid >> 2, c = tid & 3;
      const uint4 v = *reinterpret_cast<const uint4*>(&W2T[nl * HID + kk + c * 8]);
      *reinterpret_cast<uint4*>(&Bs[nl * 40 + c * 8]) = v;
    }
    __syncthreads();
    short8 af[2], bfr[4];
    const int koff = (lane >> 4) * 8;
#pragma unroll
    for (int i = 0; i < 2; i++)
      af[i] = *reinterpret_cast<const short8*>(&As[(w * 32 + i * 16 + (lane & 15)) * 40 + koff]);
#pragma unroll
    for (int j = 0; j < 4; j++)
      bfr[j] = *reinterpret_cast<const short8*>(&Bs[(j * 16 + (lane & 15)) * 40 + koff]);
#pragma unroll
    for (int i = 0; i < 2; i++)
#pragma unroll
      for (int j = 0; j < 4; j++)
        acc[i][j] = __builtin_amdgcn_mfma_f32_16x16x32_bf16(af[i], bfr[j], acc[i][j], 0, 0, 0);
  }
  float t0 = temp[0];
#pragma unroll
  for (int i = 0; i < 2; i++) {
    int rbase = row0 + w * 32 + i * 16 + (lane >> 4) * 4;
#pragma unroll
    for (int j = 0; j < 4; j++) {
      int col = j * 16 + (lane & 15);
      if (col < COUT) {
        float bv = b2[col];
#pragma unroll
        for (int r = 0; r < 4; r++) {
          int row = rbase + r;
          if (row < NN) {
            float v = acc[i][j][r] + bv;
            X0B[((long)row << 6) + col] = f2bf(v);
            HIDB[(long)row * COUT + col] = t0 * v;
          }
        }
      }
    }
  }
}

// ---------------- propagation: bf16 padded rows (128 B aligned), 2 nodes/wave ----------------

__launch_bounds__(256)
__global__ void k_prop(const int* __restrict__ offs, const int2* __restrict__ epk,
                       const unsigned short* __restrict__ xin,
                       unsigned short* __restrict__ xout, float* __restrict__ hid,
                       const float* __restrict__ temp, int accidx) {
  int node = blockIdx.x * 8 + (threadIdx.x >> 5);
  if (node >= NN) return;
  int h = threadIdx.x & 31;
  int fp = h * 2;
  int s0 = offs[node], s1 = offs[node + 1];
  float a0 = 0.f, a1 = 0.f;
  int e = s0;
  for (; e + 3 < s1; e += 4) {
    int2 p0 = epk[e], p1 = epk[e + 1], p2 = epk[e + 2], p3 = epk[e + 3];
    unsigned v0 = *reinterpret_cast<const unsigned*>(&xin[((long)p0.x << 6) + fp]);
    unsigned v1 = *reinterpret_cast<const unsigned*>(&xin[((long)p1.x << 6) + fp]);
    unsigned v2 = *reinterpret_cast<const unsigned*>(&xin[((long)p2.x << 6) + fp]);
    unsigned v3 = *reinterpret_cast<const unsigned*>(&xin[((long)p3.x << 6) + fp]);
    float w0 = __int_as_float(p0.y), w1 = __int_as_float(p1.y);
    float w2 = __int_as_float(p2.y), w3 = __int_as_float(p3.y);
    a0 += w0 * __uint_as_float(v0 << 16) + w1 * __uint_as_float(v1 << 16)
        + w2 * __uint_as_float(v2 << 16) + w3 * __uint_as_float(v3 << 16);
    a1 += w0 * __uint_as_float(v0 & 0xffff0000u) + w1 * __uint_as_float(v1 & 0xffff0000u)
        + w2 * __uint_as_float(v2 & 0xffff0000u) + w3 * __uint_as_float(v3 & 0xffff0000u);
  }
  for (; e < s1; e++) {
    int2 p0 = epk[e];
    float w0 = __int_as_float(p0.y);
    unsigned v0 = *reinterpret_cast<const unsigned*>(&xin[((long)p0.x << 6) + fp]);
    a0 += w0 * __uint_as_float(v0 << 16);
    a1 += w0 * __uint_as_float(v0 & 0xffff0000u);
  }
  if (fp < COUT) {
    unsigned pk = ((unsigned)f2bf(a1) << 16) | (unsigned)f2bf(a0);
    *reinterpret_cast<unsigned*>(&xout[((long)node << 6) + fp]) = pk;
    if (accidx >= 0) {
      float t = temp[accidx];
      float2* hp = reinterpret_cast<float2*>(&hid[(long)node * COUT + fp]);
      float2 o = *hp;
      o.x += t * a0; o.y += t * a1;
      *hp = o;
    }
  }
}

// ---------------- log_softmax ----------------

__launch_bounds__(256)
__global__ void k_lsm(const float* __restrict__ hid, float* __restrict__ out) {
  int node = blockIdx.x * 4 + (threadIdx.x >> 6);
  if (node >= NN) return;
  int f = threadIdx.x & 63;
  float v = (f < COUT) ? hid[(long)node * COUT + f] : -INFINITY;
  float m = v;
#pragma unroll
  for (int o = 32; o > 0; o >>= 1) m = fmaxf(m, __shfl_xor(m, o, 64));
  float ex = (f < COUT) ? expf(v - m) : 0.f;
  float s = ex;
#pragma unroll
  for (int o = 32; o > 0; o >>= 1) s += __shfl_xor(s, o, 64);
  if (f < COUT) out[(long)node * COUT + f] = (v - m) - logf(s);
}

// ---------------- launch ----------------

extern "C" void kernel_launch(void* const* d_in, const int* in_sizes, int n_in,
                              void* d_out, int out_size, void* d_ws, size_t ws_size,
                              hipStream_t stream) {
  const float* X  = (const float*)d_in[0];
  const int* EI   = (const int*)d_in[1];
  const float* W1 = (const float*)d_in[2];
  const float* B1 = (const float*)d_in[3];
  const float* W2 = (const float*)d_in[4];
  const float* B2 = (const float*)d_in[5];
  const float* TEMP = (const float*)d_in[6];
  const int E = in_sizes[1] / 2;
  const int* src = EI;
  const int* dst = EI + E;

  char* ws = (char*)d_ws;
  size_t off = 0;
  auto alloc = [&](size_t bytes) -> void* {
    off = (off + 511) & ~(size_t)511;
    void* p = ws + off;
    off += bytes;
    return p;
  };
  unsigned short* HB  = (unsigned short*)alloc((size_t)NN * HID * 2);
  unsigned short* W1T = (unsigned short*)alloc((size_t)HID * KPAD * 2);
  unsigned short* W2T = (unsigned short*)alloc((size_t)NPADOUT * HID * 2);
  unsigned short* X0B = (unsigned short*)alloc((size_t)NN * FPAD * 2);
  unsigned short* X1B = (unsigned short*)alloc((size_t)NN * FPAD * 2);
  float* HIDB = (float*)alloc((size_t)NN * COUT * 4);
  float* DINV = (float*)alloc((size_t)NN * 4);
  int* OFFS   = (int*)alloc((size_t)(NN + 1) * 4);
  int* BLKC   = (int*)alloc((size_t)NCB2 * 4);
  int* INCL   = (int*)alloc((size_t)NCB2 * 4);
  int* SLOT   = (int*)alloc((size_t)(NCB2 + 1) * 4);
  int* BSUM   = (int*)alloc(512 * 4);
  int* BPRE   = (int*)alloc(512 * 4);
  int* PKD    = (int*)alloc((size_t)E * 4);
  unsigned char* PKS = (unsigned char*)alloc((size_t)E);
  int2* EPK   = (int2*)alloc((size_t)E * 8);

  const int chunk = (E + NBLK - 1) / NBLK;
  const int nscan = NCB2;
  const int nsa = (nscan + 1023) / 1024;

  k_p1<<<NBLK, 256, 0, stream>>>(src, dst, BLKC, E, chunk);
  k_scan_a<<<nsa, 256, 0, stream>>>(BLKC, INCL, BSUM, nscan);
  k_scan_b<<<1, 512, 0, stream>>>(BSUM, BPRE, nsa);
  k_scan_c<<<(nscan + 255) / 256, 256, 0, stream>>>(INCL, BPRE, SLOT, nscan);
  k_p2<<<NBLK, 256, 0, stream>>>(src, dst, SLOT, PKD, PKS, E, chunk);
  k_p3s<<<NC, 256, 0, stream>>>(SLOT, PKS, DINV, E);
  k_p3d<<<NC, 256, 0, stream>>>(SLOT, PKD, DINV, OFFS, EPK, E);

  k_wt<<<(HID * KPAD + NPADOUT * HID + 255) / 256, 256, 0, stream>>>(W1, W2, W1T, W2T);

  k_gemm1<<<(NN + 127) / 128, 512, 0, stream>>>(X, W1T, B1, HB);
  k_gemm2<<<(NN + 127) / 128, 256, 0, stream>>>(HB, W2T, B2, TEMP, X0B, HIDB);

  const int PB = (NN + 7) / 8;
  for (int k = 0; k < 5; k++) {
    k_prop<<<PB, 256, 0, stream>>>(OFFS, EPK, X0B, X1B, HIDB, TEMP, -1);
    k_prop<<<PB, 256, 0, stream>>>(OFFS, EPK, X1B, X0B, HIDB, TEMP, k + 1);
  }
  k_lsm<<<(NN + 3) / 4, 256, 0, stream>>>(HIDB, (float*)d_out);
}

// Round 5
// 906.681 us; speedup vs baseline: 1.5579x; 1.0744x over previous
//
#include <hip/hip_runtime.h>

#define NN 100000
#define CIN 500
#define KPAD 512
#define HID 256
#define COUT 50
#define NPADOUT 64
#define FPAD 64                        // padded feature-row length for x_k (128 B)

#define NBLK 256                       // edge-chunk blocks for P1/P2
#define CB 128                         // nodes per coarse bucket
#define NC ((NN + CB - 1) / CB)        // 782 coarse buckets
#define NCB (NC * NBLK)                // per-(bucket,block) counts
#define NCB2 (2 * NCB)                 // dst + src parts

typedef __attribute__((ext_vector_type(8))) short short8;
typedef __attribute__((ext_vector_type(4))) float f32x4;

static __device__ __forceinline__ unsigned short f2bf(float f) {
  union { float f; unsigned u; } v; v.f = f;
  unsigned r = (v.u + 0x7fffu + ((v.u >> 16) & 1u)) >> 16;
  return (unsigned short)r;
}

static __device__ __forceinline__ int slotAt(const int* __restrict__ incl,
                                             const int* __restrict__ bpre, int g) {
  return g ? incl[g - 1] + bpre[(g - 1) >> 10] : 0;
}

// ---------------- build P1: coarse histograms (src & dst), LDS-privatized ----------------

__launch_bounds__(256)
__global__ void k_p1(const int* __restrict__ src, const int* __restrict__ dst,
                     int* __restrict__ blk_cnt, int E, int chunk) {
  __shared__ int bd[NC], bs[NC];
  int tid = threadIdx.x;
  for (int i = tid; i < NC; i += 256) { bd[i] = 0; bs[i] = 0; }
  __syncthreads();
  int e0 = blockIdx.x * chunk, e1 = min(E, e0 + chunk);
  for (int e = e0 + tid; e < e1; e += 256) {
    atomicAdd(&bd[dst[e] >> 7], 1);
    atomicAdd(&bs[src[e] >> 7], 1);
  }
  __syncthreads();
  for (int i = tid; i < NC; i += 256) {
    blk_cnt[i * NBLK + blockIdx.x] = bd[i];
    blk_cnt[NCB + i * NBLK + blockIdx.x] = bs[i];
  }
}

// ---------------- scan over NCB2 counts ----------------

__global__ void k_scan_a(const int* __restrict__ hist, int* __restrict__ incl,
                         int* __restrict__ bsum, int n) {
  __shared__ int ts[256];
  int tid = threadIdx.x;
  int base = blockIdx.x * 1024 + tid * 4;
  int a0 = 0, a1 = 0, a2 = 0, a3 = 0;
  if (base + 3 < n) {
    a0 = hist[base]; a1 = hist[base + 1]; a2 = hist[base + 2]; a3 = hist[base + 3];
  } else {
    if (base     < n) a0 = hist[base];
    if (base + 1 < n) a1 = hist[base + 1];
    if (base + 2 < n) a2 = hist[base + 2];
    if (base + 3 < n) a3 = hist[base + 3];
  }
  a1 += a0; a2 += a1; a3 += a2;
  ts[tid] = a3;
  __syncthreads();
  for (int o = 1; o < 256; o <<= 1) {
    int v = ts[tid];
    if (tid >= o) v += ts[tid - o];
    __syncthreads();
    ts[tid] = v;
    __syncthreads();
  }
  int ex = tid ? ts[tid - 1] : 0;
  if (base     < n) incl[base]     = a0 + ex;
  if (base + 1 < n) incl[base + 1] = a1 + ex;
  if (base + 2 < n) incl[base + 2] = a2 + ex;
  if (base + 3 < n) incl[base + 3] = a3 + ex;
  if (tid == 255) bsum[blockIdx.x] = ts[255];
}

__global__ void k_scan_b(const int* __restrict__ bsum, int* __restrict__ bpre, int nb) {
  __shared__ int s[512];
  int tid = threadIdx.x;
  s[tid] = (tid < nb) ? bsum[tid] : 0;
  __syncthreads();
  for (int o = 1; o < 512; o <<= 1) {
    int v = s[tid];
    if (tid >= o) v += s[tid - o];
    __syncthreads();
    s[tid] = v;
    __syncthreads();
  }
  if (tid < nb) bpre[tid] = tid ? s[tid - 1] : 0;
}

// ---------------- build P2: scatter edges into coarse buckets (no global atomics) ----------------

__launch_bounds__(256)
__global__ void k_p2(const int* __restrict__ src, const int* __restrict__ dst,
                     const int* __restrict__ incl, const int* __restrict__ bpre,
                     int* __restrict__ pkd, unsigned char* __restrict__ pks, int E, int chunk) {
  __shared__ int cd[NC], cs[NC];
  int tid = threadIdx.x;
  for (int i = tid; i < NC; i += 256) {
    cd[i] = slotAt(incl, bpre, i * NBLK + blockIdx.x);
    cs[i] = slotAt(incl, bpre, NCB + i * NBLK + blockIdx.x) - E;
  }
  __syncthreads();
  int e0 = blockIdx.x * chunk, e1 = min(E, e0 + chunk);
  for (int e = e0 + tid; e < e1; e += 256) {
    int s = src[e], d = dst[e];
    int pd = atomicAdd(&cd[d >> 7], 1);
    pkd[pd] = (s << 7) | (d & 127);
    int ps = atomicAdd(&cs[s >> 7], 1);
    pks[ps] = (unsigned char)(s & 127);
  }
}

// ---------------- build P3s: fine histogram of src -> dinv ----------------

__launch_bounds__(256)
__global__ void k_p3s(const int* __restrict__ incl, const int* __restrict__ bpre,
                      const unsigned char* __restrict__ pks, float* __restrict__ dinv, int E) {
  __shared__ int hist[CB];
  int b = blockIdx.x, tid = threadIdx.x;
  if (tid < CB) hist[tid] = 0;
  __syncthreads();
  int s0 = slotAt(incl, bpre, NCB + b * NBLK) - E;
  int s1 = slotAt(incl, bpre, NCB + (b + 1) * NBLK) - E;
  for (int e = s0 + tid; e < s1; e += 256) atomicAdd(&hist[pks[e]], 1);
  __syncthreads();
  if (tid < CB) {
    int node = b * CB + tid;
    if (node < NN) {
      int c = hist[tid];
      dinv[node] = c > 0 ? rsqrtf((float)c) : 0.f;
    }
  }
}

// ---------------- build P3d: fine sort by dst -> offs + interleaved (src,norm) CSR ----------------

__launch_bounds__(256)
__global__ void k_p3d(const int* __restrict__ incl, const int* __restrict__ bpre,
                      const int* __restrict__ pkd, const float* __restrict__ dinv,
                      int* __restrict__ offs, int2* __restrict__ epk, int E) {
  __shared__ int hist[CB], base[CB], cur[CB];
  int b = blockIdx.x, tid = threadIdx.x;
  if (tid < CB) hist[tid] = 0;
  __syncthreads();
  int s0 = slotAt(incl, bpre, b * NBLK);
  int s1 = slotAt(incl, bpre, (b + 1) * NBLK);
  for (int e = s0 + tid; e < s1; e += 256) atomicAdd(&hist[pkd[e] & 127], 1);
  __syncthreads();
  if (tid == 0) {
    int acc = s0;
    for (int i = 0; i < CB; i++) { base[i] = acc; cur[i] = acc; acc += hist[i]; }
  }
  __syncthreads();
  if (tid < CB) {
    int node = b * CB + tid;
    if (node < NN) offs[node] = base[tid];
  }
  if (b == gridDim.x - 1 && tid == 0) offs[NN] = E;
  for (int e = s0 + tid; e < s1; e += 256) {
    int pk = pkd[e];
    int fine = pk & 127, s = pk >> 7;
    int pos = atomicAdd(&cur[fine], 1);
    float nm = dinv[s] * dinv[b * CB + fine];
    epk[pos] = make_int2(s, __float_as_int(nm));
  }
}

// ---------------- weight transpose+convert (merged) ----------------

__global__ void k_wt(const float* __restrict__ W1, const float* __restrict__ W2,
                     unsigned short* __restrict__ W1T, unsigned short* __restrict__ W2T) {
  int idx = blockIdx.x * 256 + threadIdx.x;
  if (idx < HID * KPAD) {
    int n = idx >> 9, k = idx & 511;
    W1T[idx] = (k < CIN) ? f2bf(W1[(long)k * HID + n]) : (unsigned short)0;
  } else if (idx < HID * KPAD + NPADOUT * HID) {
    int i2 = idx - HID * KPAD;
    int n = i2 >> 8, k = i2 & 255;
    W2T[i2] = (n < COUT) ? f2bf(W2[(long)k * COUT + n]) : (unsigned short)0;
  }
}

// ---------------- fused MLP: h = relu(xW1+b1); out = hW2+b2 -> X0B(bf16) & HIDB ----------------
// K-loop identical to the proven R3 gemm1 (single-buffered). Epilogue round-trips the
// h-tile through LDS in two 64-row phases and does the tiny second GEMM in-block.

__launch_bounds__(512)
__global__ void k_mlp(const float* __restrict__ X, const unsigned short* __restrict__ W1T,
                      const float* __restrict__ b1, const unsigned short* __restrict__ W2T,
                      const float* __restrict__ b2, const float* __restrict__ temp,
                      unsigned short* __restrict__ X0B, float* __restrict__ HIDB) {
  __shared__ unsigned short smem[64 * 264];     // 33 KB: K-loop As/Bs, then Hs per phase
  unsigned short* As = smem;                    // 128*40 = 5120
  unsigned short* Bs = smem + 128 * 40;         // 256*40 = 10240 (total 15360 <= 16896)
  const int tid = threadIdx.x;
  const int lane = tid & 63, w = tid >> 6;
  const int wr = w >> 2, wc = w & 3;
  const int row0 = blockIdx.x * 128;
  f32x4 acc[4][4] = {};
  const int sr = tid >> 3, sc = tid & 7;
  const int br = tid >> 2, bc = tid & 3;

  for (int kk = 0; kk < KPAD; kk += 32) {
    __syncthreads();
#pragma unroll
    for (int p = 0; p < 2; p++) {
      int r = sr + p * 64;
      int grow = row0 + r;
      int gk = kk + sc * 4;
      ushort4 val;
      if (grow < NN && gk < CIN) {
        const float4 f = *reinterpret_cast<const float4*>(&X[(long)grow * CIN + gk]);
        val.x = f2bf(f.x); val.y = f2bf(f.y); val.z = f2bf(f.z); val.w = f2bf(f.w);
      } else {
        val.x = val.y = val.z = val.w = 0;
      }
      *reinterpret_cast<ushort4*>(&As[r * 40 + sc * 4]) = val;
    }
#pragma unroll
    for (int p = 0; p < 2; p++) {
      int nl = br + p * 128;
      const uint4 v = *reinterpret_cast<const uint4*>(&W1T[(long)nl * KPAD + kk + bc * 8]);
      *reinterpret_cast<uint4*>(&Bs[nl * 40 + bc * 8]) = v;
    }
    __syncthreads();
    short8 af[4], bfr[4];
    const int koff = (lane >> 4) * 8;
#pragma unroll
    for (int i = 0; i < 4; i++)
      af[i] = *reinterpret_cast<const short8*>(&As[(wr * 64 + i * 16 + (lane & 15)) * 40 + koff]);
#pragma unroll
    for (int j = 0; j < 4; j++)
      bfr[j] = *reinterpret_cast<const short8*>(&Bs[(wc * 64 + j * 16 + (lane & 15)) * 40 + koff]);
#pragma unroll
    for (int i = 0; i < 4; i++)
#pragma unroll
      for (int j = 0; j < 4; j++)
        acc[i][j] = __builtin_amdgcn_mfma_f32_16x16x32_bf16(af[i], bfr[j], acc[i][j], 0, 0, 0);
  }

  // ---- epilogue: two 64-row phases through LDS, then h @ W2 ----
  unsigned short* Hs = smem;                    // 64 rows x 264 (stride pad)
  const float t0 = temp[0];
  const int rt = w >> 1;                        // row tile (16 rows) within the 64-row phase
  const int jh = w & 1;                         // col half of NPADOUT
#pragma unroll
  for (int ph = 0; ph < 2; ph++) {
    __syncthreads();                            // previous-phase Hs / K-loop LDS reads done
    if (wr == ph) {
#pragma unroll
      for (int i = 0; i < 4; i++) {
        int lr = i * 16 + (lane >> 4) * 4;      // local row 0..63 in this phase
#pragma unroll
        for (int j = 0; j < 4; j++) {
          int col = wc * 64 + j * 16 + (lane & 15);
          float bv = b1[col];
#pragma unroll
          for (int r = 0; r < 4; r++) {
            float v = acc[i][j][r] + bv;
            v = v > 0.f ? v : 0.f;
            Hs[(lr + r) * 264 + col] = f2bf(v);
          }
        }
      }
    }
    __syncthreads();
    f32x4 acc2[2] = {};
    const int koff = (lane >> 4) * 8;
    for (int kk = 0; kk < HID; kk += 32) {
      short8 a = *reinterpret_cast<const short8*>(&Hs[(rt * 16 + (lane & 15)) * 264 + kk + koff]);
#pragma unroll
      for (int jj = 0; jj < 2; jj++) {
        int n = (jh * 2 + jj) * 16 + (lane & 15);
        short8 b = *reinterpret_cast<const short8*>(&W2T[n * HID + kk + koff]);
        acc2[jj] = __builtin_amdgcn_mfma_f32_16x16x32_bf16(a, b, acc2[jj], 0, 0, 0);
      }
    }
#pragma unroll
    for (int jj = 0; jj < 2; jj++) {
      int col = (jh * 2 + jj) * 16 + (lane & 15);
      float bv = (col < COUT) ? b2[col] : 0.f;  // W2T pad rows are zero -> v = 0 for pad cols
#pragma unroll
      for (int r = 0; r < 4; r++) {
        int row = row0 + ph * 64 + rt * 16 + (lane >> 4) * 4 + r;
        if (row < NN) {
          float v = acc2[jj][r] + bv;
          X0B[((long)row << 6) + col] = f2bf(v);
          if (col < COUT) HIDB[(long)row * COUT + col] = t0 * v;
        }
      }
    }
  }
}

// ---------------- propagation: bf16 padded rows (128 B aligned), 2 nodes/wave ----------------

__launch_bounds__(256)
__global__ void k_prop(const int* __restrict__ offs, const int2* __restrict__ epk,
                       const unsigned short* __restrict__ xin,
                       unsigned short* __restrict__ xout, float* __restrict__ hid,
                       const float* __restrict__ temp, int accidx) {
  int node = blockIdx.x * 8 + (threadIdx.x >> 5);
  if (node >= NN) return;
  int h = threadIdx.x & 31;
  int fp = h * 2;
  int s0 = offs[node], s1 = offs[node + 1];
  float a0 = 0.f, a1 = 0.f;
  int e = s0;
  for (; e + 7 < s1; e += 8) {
    int2 p[8];
#pragma unroll
    for (int q = 0; q < 8; q++) p[q] = epk[e + q];
    unsigned v[8];
#pragma unroll
    for (int q = 0; q < 8; q++)
      v[q] = *reinterpret_cast<const unsigned*>(&xin[((long)p[q].x << 6) + fp]);
#pragma unroll
    for (int q = 0; q < 8; q++) {
      float wq = __int_as_float(p[q].y);
      a0 += wq * __uint_as_float(v[q] << 16);
      a1 += wq * __uint_as_float(v[q] & 0xffff0000u);
    }
  }
  for (; e + 3 < s1; e += 4) {
    int2 p0 = epk[e], p1 = epk[e + 1], p2 = epk[e + 2], p3 = epk[e + 3];
    unsigned v0 = *reinterpret_cast<const unsigned*>(&xin[((long)p0.x << 6) + fp]);
    unsigned v1 = *reinterpret_cast<const unsigned*>(&xin[((long)p1.x << 6) + fp]);
    unsigned v2 = *reinterpret_cast<const unsigned*>(&xin[((long)p2.x << 6) + fp]);
    unsigned v3 = *reinterpret_cast<const unsigned*>(&xin[((long)p3.x << 6) + fp]);
    float w0 = __int_as_float(p0.y), w1 = __int_as_float(p1.y);
    float w2 = __int_as_float(p2.y), w3 = __int_as_float(p3.y);
    a0 += w0 * __uint_as_float(v0 << 16) + w1 * __uint_as_float(v1 << 16)
        + w2 * __uint_as_float(v2 << 16) + w3 * __uint_as_float(v3 << 16);
    a1 += w0 * __uint_as_float(v0 & 0xffff0000u) + w1 * __uint_as_float(v1 & 0xffff0000u)
        + w2 * __uint_as_float(v2 & 0xffff0000u) + w3 * __uint_as_float(v3 & 0xffff0000u);
  }
  for (; e < s1; e++) {
    int2 p0 = epk[e];
    float w0 = __int_as_float(p0.y);
    unsigned v0 = *reinterpret_cast<const unsigned*>(&xin[((long)p0.x << 6) + fp]);
    a0 += w0 * __uint_as_float(v0 << 16);
    a1 += w0 * __uint_as_float(v0 & 0xffff0000u);
  }
  if (fp < COUT) {
    unsigned pk = ((unsigned)f2bf(a1) << 16) | (unsigned)f2bf(a0);
    *reinterpret_cast<unsigned*>(&xout[((long)node << 6) + fp]) = pk;
    if (accidx >= 0) {
      float t = temp[accidx];
      float2* hp = reinterpret_cast<float2*>(&hid[(long)node * COUT + fp]);
      float2 o = *hp;
      o.x += t * a0; o.y += t * a1;
      *hp = o;
    }
  }
}

// ---------------- log_softmax ----------------

__launch_bounds__(256)
__global__ void k_lsm(const float* __restrict__ hid, float* __restrict__ out) {
  int node = blockIdx.x * 4 + (threadIdx.x >> 6);
  if (node >= NN) return;
  int f = threadIdx.x & 63;
  float v = (f < COUT) ? hid[(long)node * COUT + f] : -INFINITY;
  float m = v;
#pragma unroll
  for (int o = 32; o > 0; o >>= 1) m = fmaxf(m, __shfl_xor(m, o, 64));
  float ex = (f < COUT) ? expf(v - m) : 0.f;
  float s = ex;
#pragma unroll
  for (int o = 32; o > 0; o >>= 1) s += __shfl_xor(s, o, 64);
  if (f < COUT) out[(long)node * COUT + f] = (v - m) - logf(s);
}

// ---------------- launch ----------------

extern "C" void kernel_launch(void* const* d_in, const int* in_sizes, int n_in,
                              void* d_out, int out_size, void* d_ws, size_t ws_size,
                              hipStream_t stream) {
  const float* X  = (const float*)d_in[0];
  const int* EI   = (const int*)d_in[1];
  const float* W1 = (const float*)d_in[2];
  const float* B1 = (const float*)d_in[3];
  const float* W2 = (const float*)d_in[4];
  const float* B2 = (const float*)d_in[5];
  const float* TEMP = (const float*)d_in[6];
  const int E = in_sizes[1] / 2;
  const int* src = EI;
  const int* dst = EI + E;

  char* ws = (char*)d_ws;
  size_t off = 0;
  auto alloc = [&](size_t bytes) -> void* {
    off = (off + 511) & ~(size_t)511;
    void* p = ws + off;
    off += bytes;
    return p;
  };
  unsigned short* W1T = (unsigned short*)alloc((size_t)HID * KPAD * 2);
  unsigned short* W2T = (unsigned short*)alloc((size_t)NPADOUT * HID * 2);
  unsigned short* X0B = (unsigned short*)alloc((size_t)NN * FPAD * 2);
  unsigned short* X1B = (unsigned short*)alloc((size_t)NN * FPAD * 2);
  float* HIDB = (float*)alloc((size_t)NN * COUT * 4);
  float* DINV = (float*)alloc((size_t)NN * 4);
  int* OFFS   = (int*)alloc((size_t)(NN + 1) * 4);
  int* BLKC   = (int*)alloc((size_t)NCB2 * 4);
  int* INCL   = (int*)alloc((size_t)NCB2 * 4);
  int* BSUM   = (int*)alloc(512 * 4);
  int* BPRE   = (int*)alloc(512 * 4);
  int* PKD    = (int*)alloc((size_t)E * 4);
  unsigned char* PKS = (unsigned char*)alloc((size_t)E);
  int2* EPK   = (int2*)alloc((size_t)E * 8);

  const int chunk = (E + NBLK - 1) / NBLK;
  const int nsa = (NCB2 + 1023) / 1024;

  k_p1<<<NBLK, 256, 0, stream>>>(src, dst, BLKC, E, chunk);
  k_scan_a<<<nsa, 256, 0, stream>>>(BLKC, INCL, BSUM, NCB2);
  k_scan_b<<<1, 512, 0, stream>>>(BSUM, BPRE, nsa);
  k_p2<<<NBLK, 256, 0, stream>>>(src, dst, INCL, BPRE, PKD, PKS, E, chunk);
  k_p3s<<<NC, 256, 0, stream>>>(INCL, BPRE, PKS, DINV, E);
  k_p3d<<<NC, 256, 0, stream>>>(INCL, BPRE, PKD, DINV, OFFS, EPK, E);

  k_wt<<<(HID * KPAD + NPADOUT * HID + 255) / 256, 256, 0, stream>>>(W1, W2, W1T, W2T);

  k_mlp<<<(NN + 127) / 128, 512, 0, stream>>>(X, W1T, B1, W2T, B2, TEMP, X0B, HIDB);

  const int PB = (NN + 7) / 8;
  for (int k = 0; k < 5; k++) {
    k_prop<<<PB, 256, 0, stream>>>(OFFS, EPK, X0B, X1B, HIDB, TEMP, -1);
    k_prop<<<PB, 256, 0, stream>>>(OFFS, EPK, X1B, X0B, HIDB, TEMP, k + 1);
  }
  k_lsm<<<(NN + 3) / 4, 256, 0, stream>>>(HIDB, (float*)d_out);
}